// Round 6
// baseline (4103.895 us; speedup 1.0000x reference)
//
#include <hip/hip_runtime.h>

#define NB 3
#define HIDDEN 256
#define INDIM 128
#define NGRAPH 256
#define NCLS 10
#define NMAX 50048
#define EMAX 800000

typedef unsigned long long ull;

// ---- static device scratch (harness d_ws < needed; statics proven to work in r5) ----
__device__ float g_states[(size_t)NB * NMAX * HIDDEN];
__device__ float g_props [(size_t)NB * NMAX * HIDDEN];
__device__ float g_agg   [(size_t)NMAX * HIDDEN];   // layer0 uses as [n][128]
__device__ float g_fin   [NGRAPH * HIDDEN];
__device__ float g_dinv  [NMAX];
__device__ float g_ewts  [EMAX];
__device__ int   g_rowptr[NMAX + 1];
__device__ int   g_cidx  [EMAX];
__device__ int   g_cnt   [NMAX];
__device__ int   g_gs    [NGRAPH];
__device__ int   g_gc    [NGRAPH];

__device__ __forceinline__ float relu_f(float x) { return x > 0.f ? x : 0.f; }

// ---------------- init / CSR build ----------------
__global__ void zero_cnt_k(int n) {
    int i = blockIdx.x * 256 + threadIdx.x;
    if (i < n) g_cnt[i] = 0;
}
__global__ void zero_gk() {
    int i = threadIdx.x;  // 256 threads
    g_gs[i] = 0; g_gc[i] = 0;
}
__global__ void count_edges_k(const int* __restrict__ col, int E) {
    int i = blockIdx.x * 256 + threadIdx.x;
    if (i < E) atomicAdd(&g_cnt[col[i]], 1);
}
__global__ void dinv_k(int n) {
    int i = blockIdx.x * 256 + threadIdx.x;
    if (i < n) g_dinv[i] = rsqrtf((float)(g_cnt[i] + 1));  // +1 self loop
}
__global__ __launch_bounds__(1024) void scan_k(int n) {
    __shared__ int sm[1024];
    __shared__ int carry_s;
    int t = threadIdx.x;
    if (t == 0) carry_s = 0;
    __syncthreads();
    for (int base = 0; base < n; base += 1024) {
        int i = base + t;
        int v = (i < n) ? g_cnt[i] : 0;
        sm[t] = v;
        __syncthreads();
        for (int off = 1; off < 1024; off <<= 1) {
            int u = (t >= off) ? sm[t - off] : 0;
            __syncthreads();
            sm[t] += u;
            __syncthreads();
        }
        int incl = sm[t];
        int c0 = carry_s;
        if (i < n) g_rowptr[i] = c0 + incl - v;  // exclusive
        __syncthreads();
        if (t == 0) carry_s += sm[1023];
        __syncthreads();
    }
    if (t == 0) g_rowptr[n] = carry_s;
}
__global__ void fill_csr_k(const int* __restrict__ row, const int* __restrict__ col, int E) {
    int i = blockIdx.x * 256 + threadIdx.x;
    if (i >= E) return;
    int r = row[i], c = col[i];
    int pos = g_rowptr[c] + atomicAdd(&g_cnt[c], 1);
    g_cidx[pos] = r;
    g_ewts[pos] = g_dinv[r] * g_dinv[c];
}

// ---------------- aggregation (f32) ----------------
// g_agg[c] = dinv[c]^2 * S[c] + sum_e w_e * S[src_e]
__global__ __launch_bounds__(256) void agg256_k(size_t src_off, int n) {
    int node = blockIdx.x * 4 + (threadIdx.x >> 6);
    if (node >= n) return;
    int lane = threadIdx.x & 63;
    const float4* Xv = (const float4*)(g_states + src_off);
    size_t off = (size_t)node * 64 + lane;
    float di = g_dinv[node];
    float w0 = di * di;
    float4 a = Xv[off];
    float4 acc;
    acc.x = w0 * a.x; acc.y = w0 * a.y; acc.z = w0 * a.z; acc.w = w0 * a.w;
    int e0 = g_rowptr[node], e1 = g_rowptr[node + 1];
    for (int e = e0; e < e1; ++e) {
        int s = g_cidx[e];
        float w = g_ewts[e];
        float4 v = Xv[(size_t)s * 64 + lane];
        acc.x += w * v.x; acc.y += w * v.y; acc.z += w * v.z; acc.w += w * v.w;
    }
    ((float4*)g_agg)[off] = acc;
}

// layer-0: X = f32 input x, 128-dim; writes g_agg as [n][128]
__global__ __launch_bounds__(256) void agg128_k(const float* __restrict__ X, int n) {
    int node = blockIdx.x * 4 + (threadIdx.x >> 6);
    if (node >= n) return;
    int lane = threadIdx.x & 63;
    const float2* Xv = (const float2*)X;
    size_t off = (size_t)node * 64 + lane;
    float di = g_dinv[node];
    float w0 = di * di;
    float2 a = Xv[off];
    float ax = w0 * a.x, ay = w0 * a.y;
    int e0 = g_rowptr[node], e1 = g_rowptr[node + 1];
    for (int e = e0; e < e1; ++e) {
        int s = g_cidx[e];
        float w = g_ewts[e];
        float2 v = Xv[(size_t)s * 64 + lane];
        ax += w * v.x; ay += w * v.y;
    }
    float2 o; o.x = ax; o.y = ay;
    ((float2*)g_agg)[off] = o;
}

// ---------------- GEMM + bias + relu: g_props[out_off + r*256+c] = relu(g_agg @ W + bias)
template<int K>
__global__ __launch_bounds__(256) void gemm_relu_k(const float* __restrict__ W,
        const float* __restrict__ bias, size_t out_off, int n) {
    __shared__ float sA[32][64];   // [k][row]
    __shared__ float sW[32][256];  // [k][col]
    const float* A = g_agg;
    float* C = g_props + out_off;
    int t  = threadIdx.x;
    int tx = t & 15;    // cols tx*4 + j*64
    int ty = t >> 4;    // rows ty*4 .. ty*4+3
    int row0 = blockIdx.x * 64;
    float acc[4][4][4];
    #pragma unroll
    for (int i = 0; i < 4; i++)
        #pragma unroll
        for (int j = 0; j < 4; j++)
            #pragma unroll
            for (int q = 0; q < 4; q++) acc[i][j][q] = 0.f;

    int rr = t & 63;
    int kk = (t >> 6) * 8;

    for (int k0 = 0; k0 < K; k0 += 32) {
        float4 a0 = {0,0,0,0}, a1 = {0,0,0,0};
        int gr = row0 + rr;
        if (gr < n) {
            const float4* Ap = (const float4*)(A + (size_t)gr * K + k0 + kk);
            a0 = Ap[0]; a1 = Ap[1];
        }
        float4 wv[8];
        #pragma unroll
        for (int j = 0; j < 8; j++) {
            int s = t + j * 256;           // 0..2047
            int kq = s >> 6, c4 = s & 63;
            wv[j] = ((const float4*)(W + (size_t)(k0 + kq) * 256))[c4];
        }
        __syncthreads();
        sA[kk + 0][rr] = a0.x; sA[kk + 1][rr] = a0.y; sA[kk + 2][rr] = a0.z; sA[kk + 3][rr] = a0.w;
        sA[kk + 4][rr] = a1.x; sA[kk + 5][rr] = a1.y; sA[kk + 6][rr] = a1.z; sA[kk + 7][rr] = a1.w;
        #pragma unroll
        for (int j = 0; j < 8; j++) {
            int s = t + j * 256;
            int kq = s >> 6, c4 = s & 63;
            ((float4*)&sW[kq][0])[c4] = wv[j];
        }
        __syncthreads();
        #pragma unroll
        for (int k = 0; k < 32; ++k) {
            float4 av = *(const float4*)&sA[k][ty * 4];
            float am[4] = {av.x, av.y, av.z, av.w};
            #pragma unroll
            for (int j = 0; j < 4; ++j) {
                float4 w4 = *(const float4*)&sW[k][tx * 4 + j * 64];
                #pragma unroll
                for (int i = 0; i < 4; ++i) {
                    acc[i][j][0] += am[i] * w4.x;
                    acc[i][j][1] += am[i] * w4.y;
                    acc[i][j][2] += am[i] * w4.z;
                    acc[i][j][3] += am[i] * w4.w;
                }
            }
        }
        __syncthreads();
    }
    #pragma unroll
    for (int i = 0; i < 4; i++) {
        int r = row0 + ty * 4 + i;
        if (r >= n) continue;
        #pragma unroll
        for (int j = 0; j < 4; j++) {
            int c = tx * 4 + j * 64;
            float4 b4 = *(const float4*)&bias[c];
            float4 o;
            o.x = relu_f(acc[i][j][0] + b4.x);
            o.y = relu_f(acc[i][j][1] + b4.y);
            o.z = relu_f(acc[i][j][2] + b4.z);
            o.w = relu_f(acc[i][j][3] + b4.w);
            *(float4*)&C[(size_t)r * 256 + c] = o;
        }
    }
}

// ---------------- exact top-128 mask of 256 nonneg values (4/lane, 1 wave/row) ----
__device__ __forceinline__ float4 topk_masked(float4 v) {
    int lane = threadIdx.x & 63;
    unsigned u0 = __float_as_uint(v.x), u1 = __float_as_uint(v.y);
    unsigned u2 = __float_as_uint(v.z), u3 = __float_as_uint(v.w);
    unsigned mx = max(max(u0, u1), max(u2, u3));
    #pragma unroll
    for (int off = 32; off >= 1; off >>= 1)
        mx = max(mx, (unsigned)__shfl_xor((int)mx, off));
    unsigned lo = 0, hi = mx;
    int cge = 256;
    #pragma unroll 1
    while (lo < hi) {
        unsigned mid = lo + ((hi - lo + 1) >> 1);
        int c = __popcll(__ballot(u0 >= mid)) + __popcll(__ballot(u1 >= mid))
              + __popcll(__ballot(u2 >= mid)) + __popcll(__ballot(u3 >= mid));
        if (c >= 128) { lo = mid; cge = c; if (c == 128) break; }
        else hi = mid - 1;
    }
    unsigned thr = lo;
    float4 r;
    if (cge == 128) {
        r.x = (u0 >= thr) ? v.x : 0.f;
        r.y = (u1 >= thr) ? v.y : 0.f;
        r.z = (u2 >= thr) ? v.z : 0.f;
        r.w = (u3 >= thr) ? v.w : 0.f;
    } else {            // trim ties: keep lowest element indices among u == thr
        ull b0 = __ballot(u0 == thr), b1 = __ballot(u1 == thr);
        ull b2 = __ballot(u2 == thr), b3 = __ballot(u3 == thr);
        int cgt = __popcll(__ballot(u0 > thr)) + __popcll(__ballot(u1 > thr))
                + __popcll(__ballot(u2 > thr)) + __popcll(__ballot(u3 > thr));
        int need = 128 - cgt;
        ull below = (lane == 0) ? 0ull : (~0ull >> (64 - lane));
        int base = __popcll(b0 & below) + __popcll(b1 & below)
                 + __popcll(b2 & below) + __popcll(b3 & below);
        int o0 = (int)((b0 >> lane) & 1), o1 = (int)((b1 >> lane) & 1), o2 = (int)((b2 >> lane) & 1);
        int p0 = base, p1 = base + o0, p2 = p1 + o1, p3 = p2 + o2;
        r.x = (u0 > thr || (u0 == thr && p0 < need)) ? v.x : 0.f;
        r.y = (u1 > thr || (u1 == thr && p1 < need)) ? v.y : 0.f;
        r.z = (u2 > thr || (u2 == thr && p2 < need)) ? v.z : 0.f;
        r.w = (u3 > thr || (u3 == thr && p3 < need)) ? v.w : 0.f;
    }
    return r;
}

// layer 0: states <- relu(p_b + g*sum_{b'=b±1} mask(p_b'))
__global__ __launch_bounds__(256) void fuse0_k(const float* __restrict__ gate_logit, int n) {
    int node = blockIdx.x * 4 + (threadIdx.x >> 6);
    if (node >= n) return;
    int lane = threadIdx.x & 63;
    size_t stride = (size_t)n * 64;  // float4 units
    size_t off = (size_t)node * 64 + lane;
    float g = 1.f / (1.f + expf(-gate_logit[0]));
    const float4* P = (const float4*)g_props;
    float4* S = (float4*)g_states;
    float4 P0 = P[off], P1 = P[off + stride], P2 = P[off + 2 * stride];
    float4 m0 = topk_masked(P0), m1 = topk_masked(P1), m2 = topk_masked(P2);
    float4 o0, o1, o2;
    o0.x = relu_f(P0.x + g * m1.x); o0.y = relu_f(P0.y + g * m1.y);
    o0.z = relu_f(P0.z + g * m1.z); o0.w = relu_f(P0.w + g * m1.w);
    o1.x = relu_f(P1.x + g * (m0.x + m2.x)); o1.y = relu_f(P1.y + g * (m0.y + m2.y));
    o1.z = relu_f(P1.z + g * (m0.z + m2.z)); o1.w = relu_f(P1.w + g * (m0.w + m2.w));
    o2.x = relu_f(P2.x + g * m1.x); o2.y = relu_f(P2.y + g * m1.y);
    o2.z = relu_f(P2.z + g * m1.z); o2.w = relu_f(P2.w + g * m1.w);
    S[off] = o0; S[off + stride] = o1; S[off + 2 * stride] = o2;
}

// layers >=1: reads old states, in-place update (thread-local slices, safe)
__global__ __launch_bounds__(256) void fuse_k(const float* __restrict__ gate_logit, int n) {
    int node = blockIdx.x * 4 + (threadIdx.x >> 6);
    if (node >= n) return;
    int lane = threadIdx.x & 63;
    size_t stride = (size_t)n * 64;
    size_t off = (size_t)node * 64 + lane;
    float g = 1.f / (1.f + expf(-gate_logit[0]));
    const float4* P = (const float4*)g_props;
    float4* S = (float4*)g_states;
    float4 P0 = P[off], P1 = P[off + stride], P2 = P[off + 2 * stride];
    float4 S0 = S[off], S1 = S[off + stride], S2 = S[off + 2 * stride];
    float4 mp0 = topk_masked(P0), mp1 = topk_masked(P1), mp2 = topk_masked(P2);
    float4 ms0 = topk_masked(S0), ms1 = topk_masked(S1), ms2 = topk_masked(S2);
    float4 o0, o1, o2;
    // b=0: ms0 + mp1 + ms1 ; b=1: ms1 + mp0 + ms0 + mp2 + ms2 ; b=2: ms2 + mp1 + ms1
    o0.x = relu_f(P0.x + g * (ms0.x + mp1.x + ms1.x));
    o0.y = relu_f(P0.y + g * (ms0.y + mp1.y + ms1.y));
    o0.z = relu_f(P0.z + g * (ms0.z + mp1.z + ms1.z));
    o0.w = relu_f(P0.w + g * (ms0.w + mp1.w + ms1.w));
    o1.x = relu_f(P1.x + g * (ms1.x + mp0.x + ms0.x + mp2.x + ms2.x));
    o1.y = relu_f(P1.y + g * (ms1.y + mp0.y + ms0.y + mp2.y + ms2.y));
    o1.z = relu_f(P1.z + g * (ms1.z + mp0.z + ms0.z + mp2.z + ms2.z));
    o1.w = relu_f(P1.w + g * (ms1.w + mp0.w + ms0.w + mp2.w + ms2.w));
    o2.x = relu_f(P2.x + g * (ms2.x + mp1.x + ms1.x));
    o2.y = relu_f(P2.y + g * (ms2.y + mp1.y + ms1.y));
    o2.z = relu_f(P2.z + g * (ms2.z + mp1.z + ms1.z));
    o2.w = relu_f(P2.w + g * (ms2.w + mp1.w + ms1.w));
    S[off] = o0; S[off + stride] = o1; S[off + 2 * stride] = o2;
}

// ---------------- readout ----------------
__global__ void gbounds_k(const int* __restrict__ batch, int n) {
    int i = blockIdx.x * 256 + threadIdx.x;
    if (i >= n) return;
    int g = batch[i];
    atomicAdd(&g_gc[g], 1);
    if (i == 0 || batch[i - 1] != g) g_gs[g] = i;
}

__global__ __launch_bounds__(256) void greduce_k(float* __restrict__ outfin, int n) {
    int g = blockIdx.x, d = threadIdx.x;
    size_t stride = (size_t)n * 256;
    int st = g_gs[g], c = g_gc[g];
    float a = 0.f;
    for (int i = st; i < st + c; ++i) {
        size_t o = (size_t)i * 256 + d;
        a += g_states[o] + g_states[o + stride] + g_states[o + 2 * stride];
    }
    float r = a / (3.0f * (float)(c > 0 ? c : 1));
    g_fin[g * 256 + d] = r;
    outfin[(size_t)g * 256 + d] = r;   // f32 output: final embeddings
}

__global__ void logits_k(const float* __restrict__ Wc, const float* __restrict__ bc,
                         float* __restrict__ out) {
    int idx = blockIdx.x * 256 + threadIdx.x;
    if (idx >= NGRAPH * NCLS) return;
    int g = idx / NCLS, c = idx % NCLS;
    float s = bc[c];
    for (int k = 0; k < 256; ++k) s += g_fin[g * 256 + k] * Wc[k * NCLS + c];
    out[idx] = s;                      // f32 output: logits
}

// ---------------- launch ----------------
extern "C" void kernel_launch(void* const* d_in, const int* in_sizes, int n_in,
                              void* d_out, int out_size, void* d_ws, size_t ws_size,
                              hipStream_t stream) {
    const float* x       = (const float*)d_in[0];
    const int*   eidx    = (const int*)d_in[1];
    const int*   batch   = (const int*)d_in[2];
    const float* Win     = (const float*)d_in[3];
    const float* b_in    = (const float*)d_in[4];
    const float* Whid    = (const float*)d_in[5];
    const float* bhid    = (const float*)d_in[6];
    const float* gate_l  = (const float*)d_in[7];
    const float* Wc      = (const float*)d_in[8];
    const float* bc      = (const float*)d_in[9];
    float* out = (float*)d_out;

    const int n = in_sizes[0] / INDIM;       // 50000
    const int E = in_sizes[1] / 2;           // 800000
    if (n > NMAX || E > EMAX) return;
    const int* erow = eidx;
    const int* ecol = eidx + E;

    float* outfin = out + NGRAPH * NCLS;     // f32 final embeddings region of d_out

    const int TB = 256;
    dim3 b256(TB);
    int nblkN = (n + TB - 1) / TB;
    int eblk  = (E + TB - 1) / TB;
    int nblk4 = (n + 3) / 4;
    int gblk  = (n + 63) / 64;

    // --- CSR build ---
    zero_cnt_k<<<nblkN, b256, 0, stream>>>(n);
    count_edges_k<<<eblk, b256, 0, stream>>>(ecol, E);
    dinv_k<<<nblkN, b256, 0, stream>>>(n);
    scan_k<<<1, 1024, 0, stream>>>(n);
    zero_cnt_k<<<nblkN, b256, 0, stream>>>(n);
    fill_csr_k<<<eblk, b256, 0, stream>>>(erow, ecol, E);

    // --- layer 0: agg(x) shared across branches; props_b = relu(agg @ Win_b + b_in_b) ---
    agg128_k<<<nblk4, b256, 0, stream>>>(x, n);
    for (int b = 0; b < NB; ++b)
        gemm_relu_k<128><<<gblk, b256, 0, stream>>>(Win + (size_t)b * INDIM * HIDDEN,
                                                    b_in + (size_t)b * HIDDEN,
                                                    (size_t)b * n * 256, n);
    fuse0_k<<<nblk4, b256, 0, stream>>>(gate_l, n);

    // --- layers 1..3 ---
    for (int l = 1; l < 4; ++l) {
        for (int b = 0; b < NB; ++b) {
            agg256_k<<<nblk4, b256, 0, stream>>>((size_t)b * n * 256, n);
            gemm_relu_k<256><<<gblk, b256, 0, stream>>>(
                    Whid + (size_t)((l - 1) * NB + b) * HIDDEN * HIDDEN,
                    bhid + (size_t)((l - 1) * NB + b) * HIDDEN,
                    (size_t)b * n * 256, n);
        }
        fuse_k<<<nblk4, b256, 0, stream>>>(gate_l, n);
    }

    // --- readout ---
    zero_gk<<<1, 256, 0, stream>>>();
    gbounds_k<<<nblkN, b256, 0, stream>>>(batch, n);
    greduce_k<<<NGRAPH, b256, 0, stream>>>(outfin, n);
    logits_k<<<(NGRAPH * NCLS + TB - 1) / TB, b256, 0, stream>>>(Wc, bc, out);
}

// Round 7
// 3394.064 us; speedup vs baseline: 1.2091x; 1.2091x over previous
//
#include <hip/hip_runtime.h>
#include <hip/hip_fp16.h>

#define NB 3
#define HIDDEN 256
#define INDIM 128
#define NGRAPH 256
#define NCLS 10
#define NMAX 50048
#define EMAX 800000

typedef unsigned short u16;
typedef unsigned long long ull;

// ---- static device scratch; intermediates stored f16, computed f32 ----
__device__ u16   g_states[(size_t)NB * NMAX * HIDDEN];
__device__ u16   g_props [(size_t)NB * NMAX * HIDDEN];
__device__ u16   g_agg   [(size_t)NMAX * HIDDEN];   // layer0 uses as [n][128]
__device__ u16   g_xh    [(size_t)NMAX * INDIM];    // f16 copy of input x
__device__ float g_fin   [NGRAPH * HIDDEN];
__device__ float g_dinv  [NMAX];
__device__ float g_ewts  [EMAX];
__device__ int   g_rowptr[NMAX + 1];
__device__ int   g_cidx  [EMAX];
__device__ int   g_cnt   [NMAX];
__device__ int   g_gs    [NGRAPH];
__device__ int   g_gc    [NGRAPH];

union HU { u16 u; __half h; };
__device__ __forceinline__ float h2f(u16 v) { HU x; x.u = v; return __half2float(x.h); }
__device__ __forceinline__ u16 f2h(float f) { HU x; x.h = __float2half_rn(f); return x.u; }
__device__ __forceinline__ float relu_f(float x) { return x > 0.f ? x : 0.f; }

// ---------------- init / CSR build ----------------
__global__ void zero_cnt_k(int n) {
    int i = blockIdx.x * 256 + threadIdx.x;
    if (i < n) g_cnt[i] = 0;
}
__global__ void zero_gk() {
    int i = threadIdx.x;  // 256 threads
    g_gs[i] = 0; g_gc[i] = 0;
}
__global__ void cvt_xh_k(const float* __restrict__ x, int cnt) {
    int i = blockIdx.x * 256 + threadIdx.x;
    if (i < cnt) g_xh[i] = f2h(x[i]);
}
__global__ void count_edges_k(const int* __restrict__ col, int E) {
    int i = blockIdx.x * 256 + threadIdx.x;
    if (i < E) atomicAdd(&g_cnt[col[i]], 1);
}
__global__ void dinv_k(int n) {
    int i = blockIdx.x * 256 + threadIdx.x;
    if (i < n) g_dinv[i] = rsqrtf((float)(g_cnt[i] + 1));  // +1 self loop
}
__global__ __launch_bounds__(1024) void scan_k(int n) {
    __shared__ int sm[1024];
    __shared__ int carry_s;
    int t = threadIdx.x;
    if (t == 0) carry_s = 0;
    __syncthreads();
    for (int base = 0; base < n; base += 1024) {
        int i = base + t;
        int v = (i < n) ? g_cnt[i] : 0;
        sm[t] = v;
        __syncthreads();
        for (int off = 1; off < 1024; off <<= 1) {
            int u = (t >= off) ? sm[t - off] : 0;
            __syncthreads();
            sm[t] += u;
            __syncthreads();
        }
        int incl = sm[t];
        int c0 = carry_s;
        if (i < n) g_rowptr[i] = c0 + incl - v;  // exclusive
        __syncthreads();
        if (t == 0) carry_s += sm[1023];
        __syncthreads();
    }
    if (t == 0) g_rowptr[n] = carry_s;
}
__global__ void fill_csr_k(const int* __restrict__ row, const int* __restrict__ col, int E) {
    int i = blockIdx.x * 256 + threadIdx.x;
    if (i >= E) return;
    int r = row[i], c = col[i];
    int pos = g_rowptr[c] + atomicAdd(&g_cnt[c], 1);
    g_cidx[pos] = r;
    g_ewts[pos] = g_dinv[r] * g_dinv[c];
}

// ---------------- aggregation (f16 storage, f32 accumulate) ----------------
// g_agg[c] = dinv[c]^2 * S[c] + sum_e w_e * S[src_e]
__global__ __launch_bounds__(256) void agg256_k(size_t src_off, int n) {
    int node = blockIdx.x * 4 + (threadIdx.x >> 6);
    if (node >= n) return;
    int lane = threadIdx.x & 63;
    const ushort4* Xv = (const ushort4*)(g_states + src_off);
    size_t off = (size_t)node * 64 + lane;
    float di = g_dinv[node];
    float w0 = di * di;
    ushort4 a = Xv[off];
    float ax = w0 * h2f(a.x), ay = w0 * h2f(a.y), az = w0 * h2f(a.z), aw = w0 * h2f(a.w);
    int e0 = g_rowptr[node], e1 = g_rowptr[node + 1];
    for (int e = e0; e < e1; ++e) {
        int s = g_cidx[e];
        float w = g_ewts[e];
        ushort4 v = Xv[(size_t)s * 64 + lane];
        ax += w * h2f(v.x); ay += w * h2f(v.y); az += w * h2f(v.z); aw += w * h2f(v.w);
    }
    ushort4 o; o.x = f2h(ax); o.y = f2h(ay); o.z = f2h(az); o.w = f2h(aw);
    ((ushort4*)g_agg)[off] = o;
}

// layer-0: gathers f16 x (128-dim rows); writes g_agg as [n][128] f16
__global__ __launch_bounds__(256) void agg128_k(int n) {
    int node = blockIdx.x * 4 + (threadIdx.x >> 6);
    if (node >= n) return;
    int lane = threadIdx.x & 63;
    const ushort2* Xv = (const ushort2*)g_xh;
    size_t off = (size_t)node * 64 + lane;
    float di = g_dinv[node];
    float w0 = di * di;
    ushort2 a = Xv[off];
    float ax = w0 * h2f(a.x), ay = w0 * h2f(a.y);
    int e0 = g_rowptr[node], e1 = g_rowptr[node + 1];
    for (int e = e0; e < e1; ++e) {
        int s = g_cidx[e];
        float w = g_ewts[e];
        ushort2 v = Xv[(size_t)s * 64 + lane];
        ax += w * h2f(v.x); ay += w * h2f(v.y);
    }
    ushort2 o; o.x = f2h(ax); o.y = f2h(ay);
    ((ushort2*)g_agg)[off] = o;
}

// ---------------- GEMM + bias + relu: props = relu(agg(f16) @ W(f32) + bias) -> f16
template<int K>
__global__ __launch_bounds__(256) void gemm_relu_k(const float* __restrict__ W,
        const float* __restrict__ bias, size_t out_off, int n) {
    __shared__ float sA[32][64];   // [k][row]
    __shared__ float sW[32][256];  // [k][col]
    const u16* A = g_agg;
    u16* C = g_props + out_off;
    int t  = threadIdx.x;
    int tx = t & 15;    // cols tx*4 + j*64
    int ty = t >> 4;    // rows ty*4 .. ty*4+3
    int row0 = blockIdx.x * 64;
    float acc[4][4][4];
    #pragma unroll
    for (int i = 0; i < 4; i++)
        #pragma unroll
        for (int j = 0; j < 4; j++)
            #pragma unroll
            for (int q = 0; q < 4; q++) acc[i][j][q] = 0.f;

    int rr = t & 63;
    int kk = (t >> 6) * 8;

    for (int k0 = 0; k0 < K; k0 += 32) {
        float av8[8] = {0,0,0,0,0,0,0,0};
        int gr = row0 + rr;
        if (gr < n) {
            ushort4 u0 = *(const ushort4*)(A + (size_t)gr * K + k0 + kk);
            ushort4 u1 = *(const ushort4*)(A + (size_t)gr * K + k0 + kk + 4);
            av8[0] = h2f(u0.x); av8[1] = h2f(u0.y); av8[2] = h2f(u0.z); av8[3] = h2f(u0.w);
            av8[4] = h2f(u1.x); av8[5] = h2f(u1.y); av8[6] = h2f(u1.z); av8[7] = h2f(u1.w);
        }
        float4 wv[8];
        #pragma unroll
        for (int j = 0; j < 8; j++) {
            int s = t + j * 256;           // 0..2047
            int kq = s >> 6, c4 = s & 63;
            wv[j] = ((const float4*)(W + (size_t)(k0 + kq) * 256))[c4];
        }
        __syncthreads();
        #pragma unroll
        for (int j = 0; j < 8; j++) sA[kk + j][rr] = av8[j];
        #pragma unroll
        for (int j = 0; j < 8; j++) {
            int s = t + j * 256;
            int kq = s >> 6, c4 = s & 63;
            ((float4*)&sW[kq][0])[c4] = wv[j];
        }
        __syncthreads();
        #pragma unroll
        for (int k = 0; k < 32; ++k) {
            float4 av = *(const float4*)&sA[k][ty * 4];
            float am[4] = {av.x, av.y, av.z, av.w};
            #pragma unroll
            for (int j = 0; j < 4; ++j) {
                float4 w4 = *(const float4*)&sW[k][tx * 4 + j * 64];
                #pragma unroll
                for (int i = 0; i < 4; ++i) {
                    acc[i][j][0] += am[i] * w4.x;
                    acc[i][j][1] += am[i] * w4.y;
                    acc[i][j][2] += am[i] * w4.z;
                    acc[i][j][3] += am[i] * w4.w;
                }
            }
        }
        __syncthreads();
    }
    #pragma unroll
    for (int i = 0; i < 4; i++) {
        int r = row0 + ty * 4 + i;
        if (r >= n) continue;
        #pragma unroll
        for (int j = 0; j < 4; j++) {
            int c = tx * 4 + j * 64;
            float4 b4 = *(const float4*)&bias[c];
            ushort4 o;
            o.x = f2h(relu_f(acc[i][j][0] + b4.x));
            o.y = f2h(relu_f(acc[i][j][1] + b4.y));
            o.z = f2h(relu_f(acc[i][j][2] + b4.z));
            o.w = f2h(relu_f(acc[i][j][3] + b4.w));
            *(ushort4*)&C[(size_t)r * 256 + c] = o;
        }
    }
}

// ---------------- exact top-128 mask of 256 nonneg values (4/lane, 1 wave/row) ----
__device__ __forceinline__ float4 topk_masked(float4 v) {
    int lane = threadIdx.x & 63;
    unsigned u0 = __float_as_uint(v.x), u1 = __float_as_uint(v.y);
    unsigned u2 = __float_as_uint(v.z), u3 = __float_as_uint(v.w);
    unsigned mx = max(max(u0, u1), max(u2, u3));
    #pragma unroll
    for (int off = 32; off >= 1; off >>= 1)
        mx = max(mx, (unsigned)__shfl_xor((int)mx, off));
    unsigned lo = 0, hi = mx;
    int cge = 256;
    #pragma unroll 1
    while (lo < hi) {
        unsigned mid = lo + ((hi - lo + 1) >> 1);
        int c = __popcll(__ballot(u0 >= mid)) + __popcll(__ballot(u1 >= mid))
              + __popcll(__ballot(u2 >= mid)) + __popcll(__ballot(u3 >= mid));
        if (c >= 128) { lo = mid; cge = c; if (c == 128) break; }
        else hi = mid - 1;
    }
    unsigned thr = lo;
    float4 r;
    if (cge == 128) {
        r.x = (u0 >= thr) ? v.x : 0.f;
        r.y = (u1 >= thr) ? v.y : 0.f;
        r.z = (u2 >= thr) ? v.z : 0.f;
        r.w = (u3 >= thr) ? v.w : 0.f;
    } else {            // trim ties: keep lowest element indices among u == thr
        ull b0 = __ballot(u0 == thr), b1 = __ballot(u1 == thr);
        ull b2 = __ballot(u2 == thr), b3 = __ballot(u3 == thr);
        int cgt = __popcll(__ballot(u0 > thr)) + __popcll(__ballot(u1 > thr))
                + __popcll(__ballot(u2 > thr)) + __popcll(__ballot(u3 > thr));
        int need = 128 - cgt;
        ull below = (lane == 0) ? 0ull : (~0ull >> (64 - lane));
        int base = __popcll(b0 & below) + __popcll(b1 & below)
                 + __popcll(b2 & below) + __popcll(b3 & below);
        int o0 = (int)((b0 >> lane) & 1), o1 = (int)((b1 >> lane) & 1), o2 = (int)((b2 >> lane) & 1);
        int p0 = base, p1 = base + o0, p2 = p1 + o1, p3 = p2 + o2;
        r.x = (u0 > thr || (u0 == thr && p0 < need)) ? v.x : 0.f;
        r.y = (u1 > thr || (u1 == thr && p1 < need)) ? v.y : 0.f;
        r.z = (u2 > thr || (u2 == thr && p2 < need)) ? v.z : 0.f;
        r.w = (u3 > thr || (u3 == thr && p3 < need)) ? v.w : 0.f;
    }
    return r;
}

__device__ __forceinline__ float4 ld4h(const u16* p, size_t off) {
    ushort4 v = ((const ushort4*)p)[off];
    float4 r; r.x = h2f(v.x); r.y = h2f(v.y); r.z = h2f(v.z); r.w = h2f(v.w);
    return r;
}
__device__ __forceinline__ void st4h(u16* p, size_t off, float4 v) {
    ushort4 o; o.x = f2h(v.x); o.y = f2h(v.y); o.z = f2h(v.z); o.w = f2h(v.w);
    ((ushort4*)p)[off] = o;
}

// layer 0: states <- relu(p_b + g*sum_{b'=b±1} mask(p_b'))
__global__ __launch_bounds__(256) void fuse0_k(const float* __restrict__ gate_logit, int n) {
    int node = blockIdx.x * 4 + (threadIdx.x >> 6);
    if (node >= n) return;
    int lane = threadIdx.x & 63;
    size_t stride = (size_t)n * 64;  // ushort4 units
    size_t off = (size_t)node * 64 + lane;
    float g = 1.f / (1.f + expf(-gate_logit[0]));
    float4 P0 = ld4h(g_props, off), P1 = ld4h(g_props, off + stride), P2 = ld4h(g_props, off + 2 * stride);
    float4 m0 = topk_masked(P0), m1 = topk_masked(P1), m2 = topk_masked(P2);
    float4 o0, o1, o2;
    o0.x = relu_f(P0.x + g * m1.x); o0.y = relu_f(P0.y + g * m1.y);
    o0.z = relu_f(P0.z + g * m1.z); o0.w = relu_f(P0.w + g * m1.w);
    o1.x = relu_f(P1.x + g * (m0.x + m2.x)); o1.y = relu_f(P1.y + g * (m0.y + m2.y));
    o1.z = relu_f(P1.z + g * (m0.z + m2.z)); o1.w = relu_f(P1.w + g * (m0.w + m2.w));
    o2.x = relu_f(P2.x + g * m1.x); o2.y = relu_f(P2.y + g * m1.y);
    o2.z = relu_f(P2.z + g * m1.z); o2.w = relu_f(P2.w + g * m1.w);
    st4h(g_states, off, o0); st4h(g_states, off + stride, o1); st4h(g_states, off + 2 * stride, o2);
}

// layers >=1: reads old states, in-place update (thread-local slices, safe)
__global__ __launch_bounds__(256) void fuse_k(const float* __restrict__ gate_logit, int n) {
    int node = blockIdx.x * 4 + (threadIdx.x >> 6);
    if (node >= n) return;
    int lane = threadIdx.x & 63;
    size_t stride = (size_t)n * 64;
    size_t off = (size_t)node * 64 + lane;
    float g = 1.f / (1.f + expf(-gate_logit[0]));
    float4 P0 = ld4h(g_props, off), P1 = ld4h(g_props, off + stride), P2 = ld4h(g_props, off + 2 * stride);
    float4 S0 = ld4h(g_states, off), S1 = ld4h(g_states, off + stride), S2 = ld4h(g_states, off + 2 * stride);
    float4 mp0 = topk_masked(P0), mp1 = topk_masked(P1), mp2 = topk_masked(P2);
    float4 ms0 = topk_masked(S0), ms1 = topk_masked(S1), ms2 = topk_masked(S2);
    float4 o0, o1, o2;
    // b=0: ms0 + mp1 + ms1 ; b=1: ms1 + mp0 + ms0 + mp2 + ms2 ; b=2: ms2 + mp1 + ms1
    o0.x = relu_f(P0.x + g * (ms0.x + mp1.x + ms1.x));
    o0.y = relu_f(P0.y + g * (ms0.y + mp1.y + ms1.y));
    o0.z = relu_f(P0.z + g * (ms0.z + mp1.z + ms1.z));
    o0.w = relu_f(P0.w + g * (ms0.w + mp1.w + ms1.w));
    o1.x = relu_f(P1.x + g * (ms1.x + mp0.x + ms0.x + mp2.x + ms2.x));
    o1.y = relu_f(P1.y + g * (ms1.y + mp0.y + ms0.y + mp2.y + ms2.y));
    o1.z = relu_f(P1.z + g * (ms1.z + mp0.z + ms0.z + mp2.z + ms2.z));
    o1.w = relu_f(P1.w + g * (ms1.w + mp0.w + ms0.w + mp2.w + ms2.w));
    o2.x = relu_f(P2.x + g * (ms2.x + mp1.x + ms1.x));
    o2.y = relu_f(P2.y + g * (ms2.y + mp1.y + ms1.y));
    o2.z = relu_f(P2.z + g * (ms2.z + mp1.z + ms1.z));
    o2.w = relu_f(P2.w + g * (ms2.w + mp1.w + ms1.w));
    st4h(g_states, off, o0); st4h(g_states, off + stride, o1); st4h(g_states, off + 2 * stride, o2);
}

// ---------------- readout ----------------
__global__ void gbounds_k(const int* __restrict__ batch, int n) {
    int i = blockIdx.x * 256 + threadIdx.x;
    if (i >= n) return;
    int g = batch[i];
    atomicAdd(&g_gc[g], 1);
    if (i == 0 || batch[i - 1] != g) g_gs[g] = i;
}

__global__ __launch_bounds__(256) void greduce_k(float* __restrict__ outfin, int n) {
    int g = blockIdx.x, d = threadIdx.x;
    size_t stride = (size_t)n * 256;
    int st = g_gs[g], c = g_gc[g];
    float a = 0.f;
    for (int i = st; i < st + c; ++i) {
        size_t o = (size_t)i * 256 + d;
        a += h2f(g_states[o]) + h2f(g_states[o + stride]) + h2f(g_states[o + 2 * stride]);
    }
    float r = a / (3.0f * (float)(c > 0 ? c : 1));
    g_fin[g * 256 + d] = r;
    outfin[(size_t)g * 256 + d] = r;   // f32 output: final embeddings
}

__global__ void logits_k(const float* __restrict__ Wc, const float* __restrict__ bc,
                         float* __restrict__ out) {
    int idx = blockIdx.x * 256 + threadIdx.x;
    if (idx >= NGRAPH * NCLS) return;
    int g = idx / NCLS, c = idx % NCLS;
    float s = bc[c];
    for (int k = 0; k < 256; ++k) s += g_fin[g * 256 + k] * Wc[k * NCLS + c];
    out[idx] = s;                      // f32 output: logits
}

// ---------------- launch ----------------
extern "C" void kernel_launch(void* const* d_in, const int* in_sizes, int n_in,
                              void* d_out, int out_size, void* d_ws, size_t ws_size,
                              hipStream_t stream) {
    const float* x       = (const float*)d_in[0];
    const int*   eidx    = (const int*)d_in[1];
    const int*   batch   = (const int*)d_in[2];
    const float* Win     = (const float*)d_in[3];
    const float* b_in    = (const float*)d_in[4];
    const float* Whid    = (const float*)d_in[5];
    const float* bhid    = (const float*)d_in[6];
    const float* gate_l  = (const float*)d_in[7];
    const float* Wc      = (const float*)d_in[8];
    const float* bc      = (const float*)d_in[9];
    float* out = (float*)d_out;

    const int n = in_sizes[0] / INDIM;       // 50000
    const int E = in_sizes[1] / 2;           // 800000
    if (n > NMAX || E > EMAX) return;
    const int* erow = eidx;
    const int* ecol = eidx + E;

    float* outfin = out + NGRAPH * NCLS;     // f32 final embeddings region of d_out

    const int TB = 256;
    dim3 b256(TB);
    int nblkN = (n + TB - 1) / TB;
    int eblk  = (E + TB - 1) / TB;
    int nblk4 = (n + 3) / 4;
    int gblk  = (n + 63) / 64;

    // --- CSR build + x conversion ---
    zero_cnt_k<<<nblkN, b256, 0, stream>>>(n);
    cvt_xh_k<<<(n * INDIM + TB - 1) / TB, b256, 0, stream>>>(x, n * INDIM);
    count_edges_k<<<eblk, b256, 0, stream>>>(ecol, E);
    dinv_k<<<nblkN, b256, 0, stream>>>(n);
    scan_k<<<1, 1024, 0, stream>>>(n);
    zero_cnt_k<<<nblkN, b256, 0, stream>>>(n);
    fill_csr_k<<<eblk, b256, 0, stream>>>(erow, ecol, E);

    // --- layer 0: agg(x) shared across branches; props_b = relu(agg @ Win_b + b_in_b) ---
    agg128_k<<<nblk4, b256, 0, stream>>>(n);
    for (int b = 0; b < NB; ++b)
        gemm_relu_k<128><<<gblk, b256, 0, stream>>>(Win + (size_t)b * INDIM * HIDDEN,
                                                    b_in + (size_t)b * HIDDEN,
                                                    (size_t)b * n * 256, n);
    fuse0_k<<<nblk4, b256, 0, stream>>>(gate_l, n);

    // --- layers 1..3 ---
    for (int l = 1; l < 4; ++l) {
        for (int b = 0; b < NB; ++b) {
            agg256_k<<<nblk4, b256, 0, stream>>>((size_t)b * n * 256, n);
            gemm_relu_k<256><<<gblk, b256, 0, stream>>>(
                    Whid + (size_t)((l - 1) * NB + b) * HIDDEN * HIDDEN,
                    bhid + (size_t)((l - 1) * NB + b) * HIDDEN,
                    (size_t)b * n * 256, n);
        }
        fuse_k<<<nblk4, b256, 0, stream>>>(gate_l, n);
    }

    // --- readout ---
    zero_gk<<<1, 256, 0, stream>>>();
    gbounds_k<<<nblkN, b256, 0, stream>>>(batch, n);
    greduce_k<<<NGRAPH, b256, 0, stream>>>(outfin, n);
    logits_k<<<(NGRAPH * NCLS + TB - 1) / TB, b256, 0, stream>>>(Wc, bc, out);
}

// Round 9
// 1953.178 us; speedup vs baseline: 2.1011x; 1.7377x over previous
//
#include <hip/hip_runtime.h>
#include <hip/hip_fp16.h>

#define NB 3
#define HIDDEN 256
#define INDIM 128
#define NGRAPH 256
#define NCLS 10
#define NMAX 50048
#define EMAX 800000

typedef unsigned short u16;
typedef unsigned long long ull;
typedef _Float16 f16_t;
typedef f16_t f16x8 __attribute__((ext_vector_type(8)));
typedef float f32x4 __attribute__((ext_vector_type(4)));

// ---- static device scratch; intermediates stored f16, computed f32 ----
// NOTE: these symbols are referenced ONLY inside device code (host passing of
// __device__ symbol addresses was the r8 crash).
__device__ u16   g_states[(size_t)NB * NMAX * HIDDEN];
__device__ u16   g_props [(size_t)NB * NMAX * HIDDEN];
__device__ u16   g_agg3 [(size_t)NB * NMAX * HIDDEN];   // layer0 uses plane0 as [n][128]
__device__ u16   g_xh    [(size_t)NMAX * INDIM];
__device__ u16   g_whin [(size_t)NB * INDIM * HIDDEN];   // Win^T f16: [b][col][k]
__device__ u16   g_whid [(size_t)9 * HIDDEN * HIDDEN];   // Whid^T f16: [(l-1)*3+b][col][k]
__device__ float g_fin   [NGRAPH * HIDDEN];
__device__ float g_dinv  [NMAX];
__device__ float g_ewts  [EMAX];
__device__ int   g_rowptr[NMAX + 1];
__device__ int   g_cidx  [EMAX];
__device__ int   g_cnt   [NMAX];
__device__ int   g_gs    [NGRAPH];
__device__ int   g_gc    [NGRAPH];

union HU { u16 u; __half h; };
__device__ __forceinline__ float h2f(u16 v) { HU x; x.u = v; return __half2float(x.h); }
__device__ __forceinline__ u16 f2h(float f) { HU x; x.h = __float2half_rn(f); return x.u; }
__device__ __forceinline__ float relu_f(float x) { return x > 0.f ? x : 0.f; }

// ---------------- init / conversions ----------------
__global__ void zero_cnt_k(int n) {
    int i = blockIdx.x * 256 + threadIdx.x;
    if (i < n) g_cnt[i] = 0;
}
__global__ void zero_gk() {
    int i = threadIdx.x;
    g_gs[i] = 0; g_gc[i] = 0;
}
__global__ void cvt_xh_k(const float* __restrict__ x, int cnt) {
    int i = blockIdx.x * 256 + threadIdx.x;
    if (i < cnt) g_xh[i] = f2h(x[i]);
}
// src [B][K][256] row-major -> g_whin/g_whid [B][256][K] f16 (which: 0=win,1=whid)
__global__ void cvt_wt_k(const float* __restrict__ src, int which, int K, int total) {
    int i = blockIdx.x * 256 + threadIdx.x;
    if (i >= total) return;
    int kc = K * 256;
    int b = i / kc; int rem = i - b * kc;
    int k = rem >> 8; int c = rem & 255;
    u16* dst = which ? g_whid : g_whin;
    dst[(size_t)b * kc + (size_t)c * K + k] = f2h(src[i]);
}

// ---------------- CSR build ----------------
__global__ void count_edges_k(const int* __restrict__ col, int E) {
    int i = blockIdx.x * 256 + threadIdx.x;
    if (i < E) atomicAdd(&g_cnt[col[i]], 1);
}
__global__ void dinv_k(int n) {
    int i = blockIdx.x * 256 + threadIdx.x;
    if (i < n) g_dinv[i] = rsqrtf((float)(g_cnt[i] + 1));
}
__global__ __launch_bounds__(1024) void scan_k(int n) {
    __shared__ int sm[1024];
    __shared__ int carry_s;
    int t = threadIdx.x;
    if (t == 0) carry_s = 0;
    __syncthreads();
    for (int base = 0; base < n; base += 1024) {
        int i = base + t;
        int v = (i < n) ? g_cnt[i] : 0;
        sm[t] = v;
        __syncthreads();
        for (int off = 1; off < 1024; off <<= 1) {
            int u = (t >= off) ? sm[t - off] : 0;
            __syncthreads();
            sm[t] += u;
            __syncthreads();
        }
        int incl = sm[t];
        int c0 = carry_s;
        if (i < n) g_rowptr[i] = c0 + incl - v;
        __syncthreads();
        if (t == 0) carry_s += sm[1023];
        __syncthreads();
    }
    if (t == 0) g_rowptr[n] = carry_s;
}
__global__ void fill_csr_k(const int* __restrict__ row, const int* __restrict__ col, int E) {
    int i = blockIdx.x * 256 + threadIdx.x;
    if (i >= E) return;
    int r = row[i], c = col[i];
    int pos = g_rowptr[c] + atomicAdd(&g_cnt[c], 1);
    g_cidx[pos] = r;
    g_ewts[pos] = g_dinv[r] * g_dinv[c];
}

// ---------------- aggregation (all 3 branches in one pass) ----------------
__global__ __launch_bounds__(256) void agg256x3_k(int n) {
    int node = blockIdx.x * 4 + (threadIdx.x >> 6);
    if (node >= n) return;
    int lane = threadIdx.x & 63;
    size_t st  = (size_t)n * 64;      // ushort4 per state plane
    size_t stA = (size_t)NMAX * 64;   // ushort4 per agg plane
    const ushort4* Sv = (const ushort4*)g_states;
    size_t off = (size_t)node * 64 + lane;
    float di = g_dinv[node];
    float w0 = di * di;
    ushort4 a0 = Sv[off], a1 = Sv[off + st], a2 = Sv[off + 2 * st];
    float x0 = w0*h2f(a0.x), y0 = w0*h2f(a0.y), z0 = w0*h2f(a0.z), w_0 = w0*h2f(a0.w);
    float x1 = w0*h2f(a1.x), y1 = w0*h2f(a1.y), z1 = w0*h2f(a1.z), w_1 = w0*h2f(a1.w);
    float x2 = w0*h2f(a2.x), y2 = w0*h2f(a2.y), z2 = w0*h2f(a2.z), w_2 = w0*h2f(a2.w);
    int e0 = g_rowptr[node], e1 = g_rowptr[node + 1];
    for (int e = e0; e < e1; ++e) {
        int s = g_cidx[e];
        float w = g_ewts[e];
        size_t b = (size_t)s * 64 + lane;
        ushort4 v0 = Sv[b], v1 = Sv[b + st], v2 = Sv[b + 2 * st];
        x0 += w*h2f(v0.x); y0 += w*h2f(v0.y); z0 += w*h2f(v0.z); w_0 += w*h2f(v0.w);
        x1 += w*h2f(v1.x); y1 += w*h2f(v1.y); z1 += w*h2f(v1.z); w_1 += w*h2f(v1.w);
        x2 += w*h2f(v2.x); y2 += w*h2f(v2.y); z2 += w*h2f(v2.z); w_2 += w*h2f(v2.w);
    }
    ushort4* Av = (ushort4*)g_agg3;
    ushort4 o;
    o.x=f2h(x0); o.y=f2h(y0); o.z=f2h(z0); o.w=f2h(w_0); Av[off] = o;
    o.x=f2h(x1); o.y=f2h(y1); o.z=f2h(z1); o.w=f2h(w_1); Av[off + stA] = o;
    o.x=f2h(x2); o.y=f2h(y2); o.z=f2h(z2); o.w=f2h(w_2); Av[off + 2 * stA] = o;
}

// layer-0: gathers f16 x (128-dim rows); writes g_agg3 plane0 as [n][128]
__global__ __launch_bounds__(256) void agg128_k(int n) {
    int node = blockIdx.x * 4 + (threadIdx.x >> 6);
    if (node >= n) return;
    int lane = threadIdx.x & 63;
    const ushort2* Xv = (const ushort2*)g_xh;
    size_t off = (size_t)node * 64 + lane;
    float di = g_dinv[node];
    float w0 = di * di;
    ushort2 a = Xv[off];
    float ax = w0 * h2f(a.x), ay = w0 * h2f(a.y);
    int e0 = g_rowptr[node], e1 = g_rowptr[node + 1];
    for (int e = e0; e < e1; ++e) {
        int s = g_cidx[e];
        float w = g_ewts[e];
        ushort2 v = Xv[(size_t)s * 64 + lane];
        ax += w * h2f(v.x); ay += w * h2f(v.y);
    }
    ushort2 o; o.x = f2h(ax); o.y = f2h(ay);
    ((ushort2*)g_agg3)[off] = o;
}

// ---------------- MFMA GEMM: g_props[br][r][c] = relu(A[r][:] . Wt[c][:] + bias[c])
// wsel < 0: Wt = g_whin[br]; else Wt = g_whid[wsel+br]. A = g_agg3 + br*aStride.
template<int K>
__global__ __launch_bounds__(256) void gemm_mfma_k(int wsel, size_t aStride,
        const float* __restrict__ bias0, int n) {
    int br = blockIdx.y;
    const f16_t* A  = (const f16_t*)g_agg3 + (size_t)br * aStride;
    const f16_t* Wt = (wsel < 0) ? (const f16_t*)g_whin + (size_t)br * K * 256
                                 : (const f16_t*)g_whid + (size_t)(wsel + br) * K * 256;
    const float* bias = bias0 + (size_t)br * 256;
    u16* C = g_props + (size_t)br * n * 256;
    int t = threadIdx.x, l = t & 63, w = t >> 6;
    int row0 = blockIdx.x * 64;
    int c0 = w * 64;
    int mrow = l & 15;
    int kg = (l >> 4) * 8;
    f32x4 acc[4][4];
    #pragma unroll
    for (int rt = 0; rt < 4; ++rt)
        #pragma unroll
        for (int ct = 0; ct < 4; ++ct) acc[rt][ct] = (f32x4){0.f, 0.f, 0.f, 0.f};

    for (int k0 = 0; k0 < K; k0 += 32) {
        f16x8 af[4], bf[4];
        #pragma unroll
        for (int rt = 0; rt < 4; ++rt) {
            int r = row0 + rt * 16 + mrow;   // < NMAX always; stale rows masked at store
            af[rt] = *(const f16x8*)(A + (size_t)r * K + k0 + kg);
        }
        #pragma unroll
        for (int ct = 0; ct < 4; ++ct) {
            int c = c0 + ct * 16 + mrow;
            bf[ct] = *(const f16x8*)(Wt + (size_t)c * K + k0 + kg);
        }
        #pragma unroll
        for (int rt = 0; rt < 4; ++rt)
            #pragma unroll
            for (int ct = 0; ct < 4; ++ct)
                acc[rt][ct] = __builtin_amdgcn_mfma_f32_16x16x32_f16(af[rt], bf[ct], acc[rt][ct], 0, 0, 0);
    }
    int rb = (l >> 4) * 4;
    #pragma unroll
    for (int ct = 0; ct < 4; ++ct) {
        int c = c0 + ct * 16 + mrow;
        float bv = bias[c];
        #pragma unroll
        for (int rt = 0; rt < 4; ++rt) {
            #pragma unroll
            for (int q = 0; q < 4; ++q) {
                int r = row0 + rt * 16 + rb + q;
                if (r < n) C[(size_t)r * 256 + c] = f2h(relu_f(acc[rt][ct][q] + bv));
            }
        }
    }
}

// ---------------- interleaved exact top-128 masks (u16 f16-bit search, 15 fixed iters) ----
template<int CNT>
__device__ __forceinline__ void topk_multi(const ushort4* hu, const float4* v, float4* out) {
    int lane = threadIdx.x & 63;
    unsigned lo[CNT], hi[CNT]; int cge[CNT];
    #pragma unroll
    for (int s = 0; s < CNT; ++s) { lo[s] = 0; hi[s] = 0x7BFF; cge[s] = 256; }
    for (int it = 0; it < 15; ++it) {
        #pragma unroll
        for (int s = 0; s < CNT; ++s) {
            unsigned mid = (lo[s] + hi[s] + 1) >> 1;
            int c = __popcll(__ballot(hu[s].x >= mid)) + __popcll(__ballot(hu[s].y >= mid))
                  + __popcll(__ballot(hu[s].z >= mid)) + __popcll(__ballot(hu[s].w >= mid));
            if (c >= 128) { lo[s] = mid; cge[s] = c; } else hi[s] = mid - 1;
        }
    }
    #pragma unroll
    for (int s = 0; s < CNT; ++s) {
        unsigned thr = lo[s];
        unsigned a0 = hu[s].x, a1 = hu[s].y, a2 = hu[s].z, a3 = hu[s].w;
        float4 r;
        if (cge[s] == 128) {   // wave-uniform branch
            r.x = (a0 >= thr) ? v[s].x : 0.f;
            r.y = (a1 >= thr) ? v[s].y : 0.f;
            r.z = (a2 >= thr) ? v[s].z : 0.f;
            r.w = (a3 >= thr) ? v[s].w : 0.f;
        } else {               // trim ties, keep lowest element indices
            ull b0 = __ballot(a0 == thr), b1 = __ballot(a1 == thr);
            ull b2 = __ballot(a2 == thr), b3 = __ballot(a3 == thr);
            int cgt = __popcll(__ballot(a0 > thr)) + __popcll(__ballot(a1 > thr))
                    + __popcll(__ballot(a2 > thr)) + __popcll(__ballot(a3 > thr));
            int need = 128 - cgt;
            ull below = (lane == 0) ? 0ull : (~0ull >> (64 - lane));
            int base = __popcll(b0 & below) + __popcll(b1 & below)
                     + __popcll(b2 & below) + __popcll(b3 & below);
            int o0 = (int)((b0 >> lane) & 1), o1 = (int)((b1 >> lane) & 1), o2 = (int)((b2 >> lane) & 1);
            int p0 = base, p1 = base + o0, p2 = p1 + o1, p3 = p2 + o2;
            r.x = (a0 > thr || (a0 == thr && p0 < need)) ? v[s].x : 0.f;
            r.y = (a1 > thr || (a1 == thr && p1 < need)) ? v[s].y : 0.f;
            r.z = (a2 > thr || (a2 == thr && p2 < need)) ? v[s].z : 0.f;
            r.w = (a3 > thr || (a3 == thr && p3 < need)) ? v[s].w : 0.f;
        }
        out[s] = r;
    }
}

__device__ __forceinline__ float4 dec4(ushort4 h) {
    float4 r; r.x = h2f(h.x); r.y = h2f(h.y); r.z = h2f(h.z); r.w = h2f(h.w);
    return r;
}
__device__ __forceinline__ void st4h(u16* p, size_t off, float4 v) {
    ushort4 o; o.x = f2h(v.x); o.y = f2h(v.y); o.z = f2h(v.z); o.w = f2h(v.w);
    ((ushort4*)p)[off] = o;
}

// layer 0: states <- relu(p_b + g*sum mask(p_b'))
__global__ __launch_bounds__(256) void fuse0_k(const float* __restrict__ gate_logit, int n) {
    int node = blockIdx.x * 4 + (threadIdx.x >> 6);
    if (node >= n) return;
    int lane = threadIdx.x & 63;
    size_t stride = (size_t)n * 64;
    size_t off = (size_t)node * 64 + lane;
    float g = 1.f / (1.f + expf(-gate_logit[0]));
    const ushort4* P = (const ushort4*)g_props;
    ushort4 hu[3]; float4 v[3], m[3];
    hu[0] = P[off]; hu[1] = P[off + stride]; hu[2] = P[off + 2 * stride];
    v[0] = dec4(hu[0]); v[1] = dec4(hu[1]); v[2] = dec4(hu[2]);
    topk_multi<3>(hu, v, m);
    float4 o0, o1, o2;
    o0.x = relu_f(v[0].x + g * m[1].x); o0.y = relu_f(v[0].y + g * m[1].y);
    o0.z = relu_f(v[0].z + g * m[1].z); o0.w = relu_f(v[0].w + g * m[1].w);
    o1.x = relu_f(v[1].x + g * (m[0].x + m[2].x)); o1.y = relu_f(v[1].y + g * (m[0].y + m[2].y));
    o1.z = relu_f(v[1].z + g * (m[0].z + m[2].z)); o1.w = relu_f(v[1].w + g * (m[0].w + m[2].w));
    o2.x = relu_f(v[2].x + g * m[1].x); o2.y = relu_f(v[2].y + g * m[1].y);
    o2.z = relu_f(v[2].z + g * m[1].z); o2.w = relu_f(v[2].w + g * m[1].w);
    st4h(g_states, off, o0); st4h(g_states, off + stride, o1); st4h(g_states, off + 2 * stride, o2);
}

// layers >=1: m[0..2]=mask(props), m[3..5]=mask(old states)
__global__ __launch_bounds__(256) void fuse_k(const float* __restrict__ gate_logit, int n) {
    int node = blockIdx.x * 4 + (threadIdx.x >> 6);
    if (node >= n) return;
    int lane = threadIdx.x & 63;
    size_t stride = (size_t)n * 64;
    size_t off = (size_t)node * 64 + lane;
    float g = 1.f / (1.f + expf(-gate_logit[0]));
    const ushort4* P = (const ushort4*)g_props;
    const ushort4* S = (const ushort4*)g_states;
    ushort4 hu[6]; float4 v[6], m[6];
    hu[0] = P[off]; hu[1] = P[off + stride]; hu[2] = P[off + 2 * stride];
    hu[3] = S[off]; hu[4] = S[off + stride]; hu[5] = S[off + 2 * stride];
    #pragma unroll
    for (int s = 0; s < 6; ++s) v[s] = dec4(hu[s]);
    topk_multi<6>(hu, v, m);
    float4 o0, o1, o2;
    o0.x = relu_f(v[0].x + g * (m[3].x + m[1].x + m[4].x));
    o0.y = relu_f(v[0].y + g * (m[3].y + m[1].y + m[4].y));
    o0.z = relu_f(v[0].z + g * (m[3].z + m[1].z + m[4].z));
    o0.w = relu_f(v[0].w + g * (m[3].w + m[1].w + m[4].w));
    o1.x = relu_f(v[1].x + g * (m[4].x + m[0].x + m[3].x + m[2].x + m[5].x));
    o1.y = relu_f(v[1].y + g * (m[4].y + m[0].y + m[3].y + m[2].y + m[5].y));
    o1.z = relu_f(v[1].z + g * (m[4].z + m[0].z + m[3].z + m[2].z + m[5].z));
    o1.w = relu_f(v[1].w + g * (m[4].w + m[0].w + m[3].w + m[2].w + m[5].w));
    o2.x = relu_f(v[2].x + g * (m[5].x + m[1].x + m[4].x));
    o2.y = relu_f(v[2].y + g * (m[5].y + m[1].y + m[4].y));
    o2.z = relu_f(v[2].z + g * (m[5].z + m[1].z + m[4].z));
    o2.w = relu_f(v[2].w + g * (m[5].w + m[1].w + m[4].w));
    st4h(g_states, off, o0); st4h(g_states, off + stride, o1); st4h(g_states, off + 2 * stride, o2);
}

// ---------------- readout ----------------
__global__ void gbounds_k(const int* __restrict__ batch, int n) {
    int i = blockIdx.x * 256 + threadIdx.x;
    if (i >= n) return;
    int g = batch[i];
    atomicAdd(&g_gc[g], 1);
    if (i == 0 || batch[i - 1] != g) g_gs[g] = i;
}

__global__ __launch_bounds__(256) void greduce_k(float* __restrict__ outfin, int n) {
    int g = blockIdx.x, d = threadIdx.x;
    size_t stride = (size_t)n * 256;
    int st = g_gs[g], c = g_gc[g];
    float a = 0.f;
    for (int i = st; i < st + c; ++i) {
        size_t o = (size_t)i * 256 + d;
        a += h2f(g_states[o]) + h2f(g_states[o + stride]) + h2f(g_states[o + 2 * stride]);
    }
    float r = a / (3.0f * (float)(c > 0 ? c : 1));
    g_fin[g * 256 + d] = r;
    outfin[(size_t)g * 256 + d] = r;
}

__global__ void logits_k(const float* __restrict__ Wc, const float* __restrict__ bc,
                         float* __restrict__ out) {
    int idx = blockIdx.x * 256 + threadIdx.x;
    if (idx >= NGRAPH * NCLS) return;
    int g = idx / NCLS, c = idx % NCLS;
    float s = bc[c];
    for (int k = 0; k < 256; ++k) s += g_fin[g * 256 + k] * Wc[k * NCLS + c];
    out[idx] = s;
}

// ---------------- launch ----------------
extern "C" void kernel_launch(void* const* d_in, const int* in_sizes, int n_in,
                              void* d_out, int out_size, void* d_ws, size_t ws_size,
                              hipStream_t stream) {
    const float* x       = (const float*)d_in[0];
    const int*   eidx    = (const int*)d_in[1];
    const int*   batch   = (const int*)d_in[2];
    const float* Win     = (const float*)d_in[3];
    const float* b_in    = (const float*)d_in[4];
    const float* Whid    = (const float*)d_in[5];
    const float* bhid    = (const float*)d_in[6];
    const float* gate_l  = (const float*)d_in[7];
    const float* Wc      = (const float*)d_in[8];
    const float* bc      = (const float*)d_in[9];
    float* out = (float*)d_out;

    const int n = in_sizes[0] / INDIM;       // 50000
    const int E = in_sizes[1] / 2;           // 800000
    if (n > NMAX || E > EMAX) return;
    const int* erow = eidx;
    const int* ecol = eidx + E;

    float* outfin = out + NGRAPH * NCLS;

    const int TB = 256;
    dim3 b256(TB);
    int nblkN = (n + TB - 1) / TB;
    int eblk  = (E + TB - 1) / TB;
    int nblk4 = (n + 3) / 4;
    dim3 ggrid((n + 63) / 64, NB);

    // --- conversions + CSR build ---
    zero_cnt_k<<<nblkN, b256, 0, stream>>>(n);
    cvt_xh_k<<<(n * INDIM + TB - 1) / TB, b256, 0, stream>>>(x, n * INDIM);
    cvt_wt_k<<<(NB * INDIM * HIDDEN + TB - 1) / TB, b256, 0, stream>>>(Win, 0, INDIM, NB * INDIM * HIDDEN);
    cvt_wt_k<<<(9 * HIDDEN * HIDDEN + TB - 1) / TB, b256, 0, stream>>>(Whid, 1, HIDDEN, 9 * HIDDEN * HIDDEN);
    count_edges_k<<<eblk, b256, 0, stream>>>(ecol, E);
    dinv_k<<<nblkN, b256, 0, stream>>>(n);
    scan_k<<<1, 1024, 0, stream>>>(n);
    zero_cnt_k<<<nblkN, b256, 0, stream>>>(n);
    fill_csr_k<<<eblk, b256, 0, stream>>>(erow, ecol, E);

    // --- layer 0: agg(x) shared (aStride=0); props_b = relu(agg @ Win_b + b_in_b) ---
    agg128_k<<<nblk4, b256, 0, stream>>>(n);
    gemm_mfma_k<INDIM><<<ggrid, b256, 0, stream>>>(-1, (size_t)0, b_in, n);
    fuse0_k<<<nblk4, b256, 0, stream>>>(gate_l, n);

    // --- layers 1..3 ---
    for (int l = 1; l < 4; ++l) {
        agg256x3_k<<<nblk4, b256, 0, stream>>>(n);
        gemm_mfma_k<HIDDEN><<<ggrid, b256, 0, stream>>>((l - 1) * NB, (size_t)NMAX * 256,
                bhid + (size_t)(l - 1) * NB * HIDDEN, n);
        fuse_k<<<nblk4, b256, 0, stream>>>(gate_l, n);
    }

    // --- readout ---
    zero_gk<<<1, 256, 0, stream>>>();
    gbounds_k<<<nblkN, b256, 0, stream>>>(batch, n);
    greduce_k<<<NGRAPH, b256, 0, stream>>>(outfin, n);
    logits_k<<<(NGRAPH * NCLS + TB - 1) / TB, b256, 0, stream>>>(Wc, bc, out);
}

// Round 10
// 1912.373 us; speedup vs baseline: 2.1460x; 1.0213x over previous
//
#include <hip/hip_runtime.h>
#include <hip/hip_fp16.h>

#define NB 3
#define HIDDEN 256
#define INDIM 128
#define NGRAPH 256
#define NCLS 10
#define NMAX 50048
#define EMAX 800000

typedef unsigned short u16;
typedef unsigned long long ull;
typedef _Float16 f16_t;
typedef f16_t f16x8 __attribute__((ext_vector_type(8)));
typedef float f32x4 __attribute__((ext_vector_type(4)));

// ---- static device scratch; intermediates stored f16, computed f32 ----
// referenced ONLY inside device code (host passing of __device__ symbols = r8 crash)
__device__ __align__(16) u16   g_states[(size_t)NB * NMAX * HIDDEN];
__device__ __align__(16) u16   g_props [(size_t)NB * NMAX * HIDDEN];
__device__ __align__(16) u16   g_agg3 [(size_t)NB * NMAX * HIDDEN];  // layer0: plane0 = [n][128]
__device__ __align__(16) u16   g_xh    [(size_t)NMAX * INDIM];
__device__ __align__(16) u16   g_whin [(size_t)NB * INDIM * HIDDEN];  // Win^T f16 [b][col][k]
__device__ __align__(16) u16   g_whid [(size_t)9 * HIDDEN * HIDDEN];  // Whid^T f16 [(l-1)*3+b][col][k]
__device__ float g_fin   [NGRAPH * HIDDEN];
__device__ float g_dinv  [NMAX];
__device__ float g_ewts  [EMAX];
__device__ int   g_rowptr[NMAX + 1];
__device__ int   g_cidx  [EMAX];
__device__ int   g_cnt   [NMAX];
__device__ int   g_gs    [NGRAPH];
__device__ int   g_gc    [NGRAPH];

union HU { u16 u; __half h; };
__device__ __forceinline__ float h2f(u16 v) { HU x; x.u = v; return __half2float(x.h); }
__device__ __forceinline__ u16 f2h(float f) { HU x; x.h = __float2half_rn(f); return x.u; }
__device__ __forceinline__ float relu_f(float x) { return x > 0.f ? x : 0.f; }

// acc[0..7] += w * (8 f16 packed in uint4)
__device__ __forceinline__ void fma8(float* acc, uint4 v, float w) {
    unsigned uu[4] = {v.x, v.y, v.z, v.w};
    #pragma unroll
    for (int q = 0; q < 4; ++q) {
        HU lo, hi; lo.u = (u16)(uu[q] & 0xFFFFu); hi.u = (u16)(uu[q] >> 16);
        acc[q * 2 + 0] += w * __half2float(lo.h);
        acc[q * 2 + 1] += w * __half2float(hi.h);
    }
}

// ---------------- init / conversions ----------------
__global__ void zero_cnt_k(int n) {
    int i = blockIdx.x * 256 + threadIdx.x;
    if (i < n) g_cnt[i] = 0;
}
__global__ void zero_gk() {
    int i = threadIdx.x;
    g_gs[i] = 0; g_gc[i] = 0;
}
__global__ void cvt_xh_k(const float* __restrict__ x, int cnt) {
    int i = blockIdx.x * 256 + threadIdx.x;
    if (i < cnt) g_xh[i] = f2h(x[i]);
}
// src [B][K][256] row-major -> g_whin/g_whid [B][256][K] f16 (which: 0=win,1=whid)
__global__ void cvt_wt_k(const float* __restrict__ src, int which, int K, int total) {
    int i = blockIdx.x * 256 + threadIdx.x;
    if (i >= total) return;
    int kc = K * 256;
    int b = i / kc; int rem = i - b * kc;
    int k = rem >> 8; int c = rem & 255;
    u16* dst = which ? g_whid : g_whin;
    dst[(size_t)b * kc + (size_t)c * K + k] = f2h(src[i]);
}

// ---------------- CSR build ----------------
__global__ void count_edges_k(const int* __restrict__ col, int E) {
    int i = blockIdx.x * 256 + threadIdx.x;
    if (i < E) atomicAdd(&g_cnt[col[i]], 1);
}
__global__ void dinv_k(int n) {
    int i = blockIdx.x * 256 + threadIdx.x;
    if (i < n) g_dinv[i] = rsqrtf((float)(g_cnt[i] + 1));
}
__global__ __launch_bounds__(1024) void scan_k(int n) {
    __shared__ int sm[1024];
    __shared__ int carry_s;
    int t = threadIdx.x;
    if (t == 0) carry_s = 0;
    __syncthreads();
    for (int base = 0; base < n; base += 1024) {
        int i = base + t;
        int v = (i < n) ? g_cnt[i] : 0;
        sm[t] = v;
        __syncthreads();
        for (int off = 1; off < 1024; off <<= 1) {
            int u = (t >= off) ? sm[t - off] : 0;
            __syncthreads();
            sm[t] += u;
            __syncthreads();
        }
        int incl = sm[t];
        int c0 = carry_s;
        if (i < n) g_rowptr[i] = c0 + incl - v;
        __syncthreads();
        if (t == 0) carry_s += sm[1023];
        __syncthreads();
    }
    if (t == 0) g_rowptr[n] = carry_s;
}
__global__ void fill_csr_k(const int* __restrict__ row, const int* __restrict__ col, int E) {
    int i = blockIdx.x * 256 + threadIdx.x;
    if (i >= E) return;
    int r = row[i], c = col[i];
    int pos = g_rowptr[c] + atomicAdd(&g_cnt[c], 1);
    g_cidx[pos] = r;
    g_ewts[pos] = g_dinv[r] * g_dinv[c];
}

// ---------------- aggregation: 2 edges in flight via 32-lane halves ----------------
// Row = 256 f16 = 512 B = 32 lanes x uint4. Virtual edge j=0 is the self loop.
__global__ __launch_bounds__(256) void agg256x3_k(int n) {
    int node = blockIdx.x * 4 + (threadIdx.x >> 6);
    if (node >= n) return;
    int lane = threadIdx.x & 63;
    int half = lane >> 5;          // which edge of the pair
    int li   = lane & 31;          // 16B chunk within row
    size_t pstride = (size_t)n * 32;       // uint4 per state plane
    const uint4* Sv = (const uint4*)g_states;
    float acc0[8] = {0,0,0,0,0,0,0,0}, acc1[8] = {0,0,0,0,0,0,0,0}, acc2[8] = {0,0,0,0,0,0,0,0};
    int e0 = g_rowptr[node], deg = g_rowptr[node + 1] - e0;
    int m = deg + 1;
    int j = half;
    if (half == 0) {  // self term, then jump to virtual slot 2
        float di = g_dinv[node];
        float w0 = di * di;
        size_t base = (size_t)node * 32 + li;
        fma8(acc0, Sv[base], w0);
        fma8(acc1, Sv[base + pstride], w0);
        fma8(acc2, Sv[base + 2 * pstride], w0);
        j = 2;
    }
    #pragma unroll 2
    for (; j < m; j += 2) {
        int s = g_cidx[e0 + j - 1];
        float w = g_ewts[e0 + j - 1];
        size_t base = (size_t)s * 32 + li;
        uint4 v0 = Sv[base], v1 = Sv[base + pstride], v2 = Sv[base + 2 * pstride];
        fma8(acc0, v0, w); fma8(acc1, v1, w); fma8(acc2, v2, w);
    }
    // combine halves
    #pragma unroll
    for (int q = 0; q < 8; ++q) {
        acc0[q] += __shfl_xor(acc0[q], 32);
        acc1[q] += __shfl_xor(acc1[q], 32);
        acc2[q] += __shfl_xor(acc2[q], 32);
    }
    if (half == 0) {
        size_t stA = (size_t)NMAX * 32;    // uint4 per agg plane
        uint4* Av = (uint4*)g_agg3;
        uint4 o;
        unsigned* ou = (unsigned*)&o;
        #pragma unroll
        for (int q = 0; q < 4; ++q) ou[q] = (unsigned)f2h(acc0[q*2]) | ((unsigned)f2h(acc0[q*2+1]) << 16);
        Av[(size_t)node * 32 + li] = o;
        #pragma unroll
        for (int q = 0; q < 4; ++q) ou[q] = (unsigned)f2h(acc1[q*2]) | ((unsigned)f2h(acc1[q*2+1]) << 16);
        Av[(size_t)node * 32 + li + stA] = o;
        #pragma unroll
        for (int q = 0; q < 4; ++q) ou[q] = (unsigned)f2h(acc2[q*2]) | ((unsigned)f2h(acc2[q*2+1]) << 16);
        Av[(size_t)node * 32 + li + 2 * stA] = o;
    }
}

// layer-0: x rows are 128 f16 = 256 B = 16 lanes x uint4 -> 4 edges in flight
__global__ __launch_bounds__(256) void agg128_k(int n) {
    int node = blockIdx.x * 4 + (threadIdx.x >> 6);
    if (node >= n) return;
    int lane = threadIdx.x & 63;
    int grp = lane >> 4;           // 4 edge slots
    int li  = lane & 15;
    const uint4* Xv = (const uint4*)g_xh;
    float acc[8] = {0,0,0,0,0,0,0,0};
    int e0 = g_rowptr[node], deg = g_rowptr[node + 1] - e0;
    int m = deg + 1;
    int j = grp;
    if (grp == 0) {
        float di = g_dinv[node];
        fma8(acc, Xv[(size_t)node * 16 + li], di * di);
        j = 4;
    }
    #pragma unroll 2
    for (; j < m; j += 4) {
        int s = g_cidx[e0 + j - 1];
        float w = g_ewts[e0 + j - 1];
        fma8(acc, Xv[(size_t)s * 16 + li], w);
    }
    #pragma unroll
    for (int q = 0; q < 8; ++q) {
        acc[q] += __shfl_xor(acc[q], 16);
        acc[q] += __shfl_xor(acc[q], 32);
    }
    if (grp == 0) {
        uint4 o; unsigned* ou = (unsigned*)&o;
        #pragma unroll
        for (int q = 0; q < 4; ++q) ou[q] = (unsigned)f2h(acc[q*2]) | ((unsigned)f2h(acc[q*2+1]) << 16);
        ((uint4*)g_agg3)[(size_t)node * 16 + li] = o;
    }
}

// ---------------- MFMA GEMM: g_props[br][r][c] = relu(A[r][:] . Wt[c][:] + bias[c])
// wsel < 0: Wt = g_whin[br]; else Wt = g_whid[wsel+br]. A = g_agg3 + br*aStride.
template<int K>
__global__ __launch_bounds__(256) void gemm_mfma_k(int wsel, size_t aStride,
        const float* __restrict__ bias0, int n) {
    int br = blockIdx.y;
    const f16_t* A  = (const f16_t*)g_agg3 + (size_t)br * aStride;
    const f16_t* Wt = (wsel < 0) ? (const f16_t*)g_whin + (size_t)br * K * 256
                                 : (const f16_t*)g_whid + (size_t)(wsel + br) * K * 256;
    const float* bias = bias0 + (size_t)br * 256;
    u16* C = g_props + (size_t)br * n * 256;
    int t = threadIdx.x, l = t & 63, w = t >> 6;
    int row0 = blockIdx.x * 64;
    int c0 = w * 64;
    int mrow = l & 15;
    int kg = (l >> 4) * 8;
    f32x4 acc[4][4];
    #pragma unroll
    for (int rt = 0; rt < 4; ++rt)
        #pragma unroll
        for (int ct = 0; ct < 4; ++ct) acc[rt][ct] = (f32x4){0.f, 0.f, 0.f, 0.f};

    for (int k0 = 0; k0 < K; k0 += 32) {
        f16x8 af[4], bf[4];
        #pragma unroll
        for (int rt = 0; rt < 4; ++rt) {
            int r = row0 + rt * 16 + mrow;   // < NMAX always; stale rows masked at store
            af[rt] = *(const f16x8*)(A + (size_t)r * K + k0 + kg);
        }
        #pragma unroll
        for (int ct = 0; ct < 4; ++ct) {
            int c = c0 + ct * 16 + mrow;
            bf[ct] = *(const f16x8*)(Wt + (size_t)c * K + k0 + kg);
        }
        #pragma unroll
        for (int rt = 0; rt < 4; ++rt)
            #pragma unroll
            for (int ct = 0; ct < 4; ++ct)
                acc[rt][ct] = __builtin_amdgcn_mfma_f32_16x16x32_f16(af[rt], bf[ct], acc[rt][ct], 0, 0, 0);
    }
    int rb = (l >> 4) * 4;
    #pragma unroll
    for (int ct = 0; ct < 4; ++ct) {
        int c = c0 + ct * 16 + mrow;
        float bv = bias[c];
        #pragma unroll
        for (int rt = 0; rt < 4; ++rt) {
            #pragma unroll
            for (int q = 0; q < 4; ++q) {
                int r = row0 + rt * 16 + rb + q;
                if (r < n) C[(size_t)r * 256 + c] = f2h(relu_f(acc[rt][ct][q] + bv));
            }
        }
    }
}

// ---------------- interleaved exact top-128 masks (u16 f16-bit search, 15 fixed iters) ----
template<int CNT>
__device__ __forceinline__ void topk_multi(const ushort4* hu, const float4* v, float4* out) {
    int lane = threadIdx.x & 63;
    unsigned lo[CNT], hi[CNT]; int cge[CNT];
    #pragma unroll
    for (int s = 0; s < CNT; ++s) { lo[s] = 0; hi[s] = 0x7BFF; cge[s] = 256; }
    for (int it = 0; it < 15; ++it) {
        #pragma unroll
        for (int s = 0; s < CNT; ++s) {
            unsigned mid = (lo[s] + hi[s] + 1) >> 1;
            int c = __popcll(__ballot(hu[s].x >= mid)) + __popcll(__ballot(hu[s].y >= mid))
                  + __popcll(__ballot(hu[s].z >= mid)) + __popcll(__ballot(hu[s].w >= mid));
            if (c >= 128) { lo[s] = mid; cge[s] = c; } else hi[s] = mid - 1;
        }
    }
    #pragma unroll
    for (int s = 0; s < CNT; ++s) {
        unsigned thr = lo[s];
        unsigned a0 = hu[s].x, a1 = hu[s].y, a2 = hu[s].z, a3 = hu[s].w;
        float4 r;
        if (cge[s] == 128) {   // wave-uniform branch
            r.x = (a0 >= thr) ? v[s].x : 0.f;
            r.y = (a1 >= thr) ? v[s].y : 0.f;
            r.z = (a2 >= thr) ? v[s].z : 0.f;
            r.w = (a3 >= thr) ? v[s].w : 0.f;
        } else {               // trim ties, keep lowest element indices
            ull b0 = __ballot(a0 == thr), b1 = __ballot(a1 == thr);
            ull b2 = __ballot(a2 == thr), b3 = __ballot(a3 == thr);
            int cgt = __popcll(__ballot(a0 > thr)) + __popcll(__ballot(a1 > thr))
                    + __popcll(__ballot(a2 > thr)) + __popcll(__ballot(a3 > thr));
            int need = 128 - cgt;
            ull below = (lane == 0) ? 0ull : (~0ull >> (64 - lane));
            int base = __popcll(b0 & below) + __popcll(b1 & below)
                     + __popcll(b2 & below) + __popcll(b3 & below);
            int o0 = (int)((b0 >> lane) & 1), o1 = (int)((b1 >> lane) & 1), o2 = (int)((b2 >> lane) & 1);
            int p0 = base, p1 = base + o0, p2 = p1 + o1, p3 = p2 + o2;
            r.x = (a0 > thr || (a0 == thr && p0 < need)) ? v[s].x : 0.f;
            r.y = (a1 > thr || (a1 == thr && p1 < need)) ? v[s].y : 0.f;
            r.z = (a2 > thr || (a2 == thr && p2 < need)) ? v[s].z : 0.f;
            r.w = (a3 > thr || (a3 == thr && p3 < need)) ? v[s].w : 0.f;
        }
        out[s] = r;
    }
}

__device__ __forceinline__ float4 dec4(ushort4 h) {
    float4 r; r.x = h2f(h.x); r.y = h2f(h.y); r.z = h2f(h.z); r.w = h2f(h.w);
    return r;
}
__device__ __forceinline__ void st4h(u16* p, size_t off, float4 v) {
    ushort4 o; o.x = f2h(v.x); o.y = f2h(v.y); o.z = f2h(v.z); o.w = f2h(v.w);
    ((ushort4*)p)[off] = o;
}

// layer 0: states <- relu(p_b + g*sum mask(p_b'))
__global__ __launch_bounds__(256) void fuse0_k(const float* __restrict__ gate_logit, int n) {
    int node = blockIdx.x * 4 + (threadIdx.x >> 6);
    if (node >= n) return;
    int lane = threadIdx.x & 63;
    size_t stride = (size_t)n * 64;
    size_t off = (size_t)node * 64 + lane;
    float g = 1.f / (1.f + expf(-gate_logit[0]));
    const ushort4* P = (const ushort4*)g_props;
    ushort4 hu[3]; float4 v[3], m[3];
    hu[0] = P[off]; hu[1] = P[off + stride]; hu[2] = P[off + 2 * stride];
    v[0] = dec4(hu[0]); v[1] = dec4(hu[1]); v[2] = dec4(hu[2]);
    topk_multi<3>(hu, v, m);
    float4 o0, o1, o2;
    o0.x = relu_f(v[0].x + g * m[1].x); o0.y = relu_f(v[0].y + g * m[1].y);
    o0.z = relu_f(v[0].z + g * m[1].z); o0.w = relu_f(v[0].w + g * m[1].w);
    o1.x = relu_f(v[1].x + g * (m[0].x + m[2].x)); o1.y = relu_f(v[1].y + g * (m[0].y + m[2].y));
    o1.z = relu_f(v[1].z + g * (m[0].z + m[2].z)); o1.w = relu_f(v[1].w + g * (m[0].w + m[2].w));
    o2.x = relu_f(v[2].x + g * m[1].x); o2.y = relu_f(v[2].y + g * m[1].y);
    o2.z = relu_f(v[2].z + g * m[1].z); o2.w = relu_f(v[2].w + g * m[1].w);
    st4h(g_states, off, o0); st4h(g_states, off + stride, o1); st4h(g_states, off + 2 * stride, o2);
}

// layers >=1: m[0..2]=mask(props), m[3..5]=mask(old states)
__global__ __launch_bounds__(256) void fuse_k(const float* __restrict__ gate_logit, int n) {
    int node = blockIdx.x * 4 + (threadIdx.x >> 6);
    if (node >= n) return;
    int lane = threadIdx.x & 63;
    size_t stride = (size_t)n * 64;
    size_t off = (size_t)node * 64 + lane;
    float g = 1.f / (1.f + expf(-gate_logit[0]));
    const ushort4* P = (const ushort4*)g_props;
    const ushort4* S = (const ushort4*)g_states;
    ushort4 hu[6]; float4 v[6], m[6];
    hu[0] = P[off]; hu[1] = P[off + stride]; hu[2] = P[off + 2 * stride];
    hu[3] = S[off]; hu[4] = S[off + stride]; hu[5] = S[off + 2 * stride];
    #pragma unroll
    for (int s = 0; s < 6; ++s) v[s] = dec4(hu[s]);
    topk_multi<6>(hu, v, m);
    float4 o0, o1, o2;
    o0.x = relu_f(v[0].x + g * (m[3].x + m[1].x + m[4].x));
    o0.y = relu_f(v[0].y + g * (m[3].y + m[1].y + m[4].y));
    o0.z = relu_f(v[0].z + g * (m[3].z + m[1].z + m[4].z));
    o0.w = relu_f(v[0].w + g * (m[3].w + m[1].w + m[4].w));
    o1.x = relu_f(v[1].x + g * (m[4].x + m[0].x + m[3].x + m[2].x + m[5].x));
    o1.y = relu_f(v[1].y + g * (m[4].y + m[0].y + m[3].y + m[2].y + m[5].y));
    o1.z = relu_f(v[1].z + g * (m[4].z + m[0].z + m[3].z + m[2].z + m[5].z));
    o1.w = relu_f(v[1].w + g * (m[4].w + m[0].w + m[3].w + m[2].w + m[5].w));
    o2.x = relu_f(v[2].x + g * (m[5].x + m[1].x + m[4].x));
    o2.y = relu_f(v[2].y + g * (m[5].y + m[1].y + m[4].y));
    o2.z = relu_f(v[2].z + g * (m[5].z + m[1].z + m[4].z));
    o2.w = relu_f(v[2].w + g * (m[5].w + m[1].w + m[4].w));
    st4h(g_states, off, o0); st4h(g_states, off + stride, o1); st4h(g_states, off + 2 * stride, o2);
}

// ---------------- readout ----------------
__global__ void gbounds_k(const int* __restrict__ batch, int n) {
    int i = blockIdx.x * 256 + threadIdx.x;
    if (i >= n) return;
    int g = batch[i];
    atomicAdd(&g_gc[g], 1);
    if (i == 0 || batch[i - 1] != g) g_gs[g] = i;
}

__global__ __launch_bounds__(256) void greduce_k(float* __restrict__ outfin, int n) {
    int g = blockIdx.x, d = threadIdx.x;
    size_t stride = (size_t)n * 256;
    int st = g_gs[g], c = g_gc[g];
    float a = 0.f;
    for (int i = st; i < st + c; ++i) {
        size_t o = (size_t)i * 256 + d;
        a += h2f(g_states[o]) + h2f(g_states[o + stride]) + h2f(g_states[o + 2 * stride]);
    }
    float r = a / (3.0f * (float)(c > 0 ? c : 1));
    g_fin[g * 256 + d] = r;
    outfin[(size_t)g * 256 + d] = r;
}

__global__ void logits_k(const float* __restrict__ Wc, const float* __restrict__ bc,
                         float* __restrict__ out) {
    int idx = blockIdx.x * 256 + threadIdx.x;
    if (idx >= NGRAPH * NCLS) return;
    int g = idx / NCLS, c = idx % NCLS;
    float s = bc[c];
    for (int k = 0; k < 256; ++k) s += g_fin[g * 256 + k] * Wc[k * NCLS + c];
    out[idx] = s;
}

// ---------------- launch ----------------
extern "C" void kernel_launch(void* const* d_in, const int* in_sizes, int n_in,
                              void* d_out, int out_size, void* d_ws, size_t ws_size,
                              hipStream_t stream) {
    const float* x       = (const float*)d_in[0];
    const int*   eidx    = (const int*)d_in[1];
    const int*   batch   = (const int*)d_in[2];
    const float* Win     = (const float*)d_in[3];
    const float* b_in    = (const float*)d_in[4];
    const float* Whid    = (const float*)d_in[5];
    const float* bhid    = (const float*)d_in[6];
    const float* gate_l  = (const float*)d_in[7];
    const float* Wc      = (const float*)d_in[8];
    const float* bc      = (const float*)d_in[9];
    float* out = (float*)d_out;

    const int n = in_sizes[0] / INDIM;       // 50000
    const int E = in_sizes[1] / 2;           // 800000
    if (n > NMAX || E > EMAX) return;
    const int* erow = eidx;
    const int* ecol = eidx + E;

    float* outfin = out + NGRAPH * NCLS;

    const int TB = 256;
    dim3 b256(TB);
    int nblkN = (n + TB - 1) / TB;
    int eblk  = (E + TB - 1) / TB;
    int nblk4 = (n + 3) / 4;
    dim3 ggrid((n + 63) / 64, NB);

    // --- conversions + CSR build ---
    zero_cnt_k<<<nblkN, b256, 0, stream>>>(n);
    cvt_xh_k<<<(n * INDIM + TB - 1) / TB, b256, 0, stream>>>(x, n * INDIM);
    cvt_wt_k<<<(NB * INDIM * HIDDEN + TB - 1) / TB, b256, 0, stream>>>(Win, 0, INDIM, NB * INDIM * HIDDEN);
    cvt_wt_k<<<(9 * HIDDEN * HIDDEN + TB - 1) / TB, b256, 0, stream>>>(Whid, 1, HIDDEN, 9 * HIDDEN * HIDDEN);
    count_edges_k<<<eblk, b256, 0, stream>>>(ecol, E);
    dinv_k<<<nblkN, b256, 0, stream>>>(n);
    scan_k<<<1, 1024, 0, stream>>>(n);
    zero_cnt_k<<<nblkN, b256, 0, stream>>>(n);
    fill_csr_k<<<eblk, b256, 0, stream>>>(erow, ecol, E);

    // --- layer 0: agg(x) shared (aStride=0); props_b = relu(agg @ Win_b + b_in_b) ---
    agg128_k<<<nblk4, b256, 0, stream>>>(n);
    gemm_mfma_k<INDIM><<<ggrid, b256, 0, stream>>>(-1, (size_t)0, b_in, n);
    fuse0_k<<<nblk4, b256, 0, stream>>>(gate_l, n);

    // --- layers 1..3 ---
    for (int l = 1; l < 4; ++l) {
        agg256x3_k<<<nblk4, b256, 0, stream>>>(n);
        gemm_mfma_k<HIDDEN><<<ggrid, b256, 0, stream>>>((l - 1) * NB, (size_t)NMAX * 256,
                bhid + (size_t)(l - 1) * NB * HIDDEN, n);
        fuse_k<<<nblk4, b256, 0, stream>>>(gate_l, n);
    }

    // --- readout ---
    zero_gk<<<1, 256, 0, stream>>>();
    gbounds_k<<<nblkN, b256, 0, stream>>>(batch, n);
    greduce_k<<<NGRAPH, b256, 0, stream>>>(outfin, n);
    logits_k<<<(NGRAPH * NCLS + TB - 1) / TB, b256, 0, stream>>>(Wc, bc, out);
}

// Round 11
// 1868.526 us; speedup vs baseline: 2.1963x; 1.0235x over previous
//
#include <hip/hip_runtime.h>
#include <hip/hip_fp16.h>

#define NB 3
#define HIDDEN 256
#define INDIM 128
#define NGRAPH 256
#define NCLS 10
#define NMAX 50048
#define EMAX 800000

typedef unsigned short u16;
typedef unsigned long long ull;
typedef _Float16 f16_t;
typedef f16_t f16x8 __attribute__((ext_vector_type(8)));
typedef float f32x4 __attribute__((ext_vector_type(4)));

// ---- static device scratch; intermediates stored f16, computed f32 ----
// Node-interleaved layout: [node][branch][256] (1536 B per node, contiguous).
// Symbols referenced ONLY inside device code (host passing = r8 crash).
__device__ __align__(16) u16   g_states[(size_t)NMAX * NB * HIDDEN];
__device__ __align__(16) u16   g_props [(size_t)NMAX * NB * HIDDEN];
__device__ __align__(16) u16   g_agg3 [(size_t)NMAX * NB * HIDDEN];  // layer0: [node][128] compact
__device__ __align__(16) u16   g_xh    [(size_t)NMAX * INDIM];
__device__ __align__(16) u16   g_whin [(size_t)NB * INDIM * HIDDEN];  // Win^T f16 [b][col][k]
__device__ __align__(16) u16   g_whid [(size_t)9 * HIDDEN * HIDDEN];  // Whid^T f16 [(l-1)*3+b][col][k]
__device__ float g_fin   [NGRAPH * HIDDEN];
__device__ float g_dinv  [NMAX];
__device__ float g_ewts  [EMAX];
__device__ int   g_rowptr[NMAX + 1];
__device__ int   g_cidx  [EMAX];
__device__ int   g_cnt   [NMAX];
__device__ int   g_gs    [NGRAPH];
__device__ int   g_gc    [NGRAPH];

union HU { u16 u; __half h; };
__device__ __forceinline__ float h2f(u16 v) { HU x; x.u = v; return __half2float(x.h); }
__device__ __forceinline__ u16 f2h(float f) { HU x; x.h = __float2half_rn(f); return x.u; }
__device__ __forceinline__ float relu_f(float x) { return x > 0.f ? x : 0.f; }

// acc[0..7] += w * (8 f16 packed in uint4)
__device__ __forceinline__ void fma8(float* acc, uint4 v, float w) {
    unsigned uu[4] = {v.x, v.y, v.z, v.w};
    #pragma unroll
    for (int q = 0; q < 4; ++q) {
        HU lo, hi; lo.u = (u16)(uu[q] & 0xFFFFu); hi.u = (u16)(uu[q] >> 16);
        acc[q * 2 + 0] += w * __half2float(lo.h);
        acc[q * 2 + 1] += w * __half2float(hi.h);
    }
}

// ---------------- init / conversions ----------------
__global__ void zero_cnt_k(int n) {
    int i = blockIdx.x * 256 + threadIdx.x;
    if (i < n) g_cnt[i] = 0;
}
__global__ void zero_gk() {
    int i = threadIdx.x;
    g_gs[i] = 0; g_gc[i] = 0;
}
__global__ void cvt_xh_k(const float* __restrict__ x, int cnt) {
    int i = blockIdx.x * 256 + threadIdx.x;
    if (i < cnt) g_xh[i] = f2h(x[i]);
}
// src [B][K][256] row-major -> g_whin/g_whid [B][256][K] f16 (which: 0=win,1=whid)
__global__ void cvt_wt_k(const float* __restrict__ src, int which, int K, int total) {
    int i = blockIdx.x * 256 + threadIdx.x;
    if (i >= total) return;
    int kc = K * 256;
    int b = i / kc; int rem = i - b * kc;
    int k = rem >> 8; int c = rem & 255;
    u16* dst = which ? g_whid : g_whin;
    dst[(size_t)b * kc + (size_t)c * K + k] = f2h(src[i]);
}

// ---------------- CSR build ----------------
__global__ void count_edges_k(const int* __restrict__ col, int E) {
    int i = blockIdx.x * 256 + threadIdx.x;
    if (i < E) atomicAdd(&g_cnt[col[i]], 1);
}
__global__ void dinv_k(int n) {
    int i = blockIdx.x * 256 + threadIdx.x;
    if (i < n) g_dinv[i] = rsqrtf((float)(g_cnt[i] + 1));
}
__global__ __launch_bounds__(1024) void scan_k(int n) {
    __shared__ int sm[1024];
    __shared__ int carry_s;
    int t = threadIdx.x;
    if (t == 0) carry_s = 0;
    __syncthreads();
    for (int base = 0; base < n; base += 1024) {
        int i = base + t;
        int v = (i < n) ? g_cnt[i] : 0;
        sm[t] = v;
        __syncthreads();
        for (int off = 1; off < 1024; off <<= 1) {
            int u = (t >= off) ? sm[t - off] : 0;
            __syncthreads();
            sm[t] += u;
            __syncthreads();
        }
        int incl = sm[t];
        int c0 = carry_s;
        if (i < n) g_rowptr[i] = c0 + incl - v;
        __syncthreads();
        if (t == 0) carry_s += sm[1023];
        __syncthreads();
    }
    if (t == 0) g_rowptr[n] = carry_s;
}
__global__ void fill_csr_k(const int* __restrict__ row, const int* __restrict__ col, int E) {
    int i = blockIdx.x * 256 + threadIdx.x;
    if (i >= E) return;
    int r = row[i], c = col[i];
    int pos = g_rowptr[c] + atomicAdd(&g_cnt[c], 1);
    g_cidx[pos] = r;
    g_ewts[pos] = g_dinv[r] * g_dinv[c];
}

// ---------------- aggregation: interleaved layout, 2 edges in flight ----------------
// Node block = 96 uint4 (1536 B): plane p at +32*p. Virtual edge j=0 = self loop.
__global__ __launch_bounds__(256) void agg256x3_k(int n) {
    int node = blockIdx.x * 4 + (threadIdx.x >> 6);
    if (node >= n) return;
    int lane = threadIdx.x & 63;
    int half = lane >> 5;          // which edge of the pair
    int li   = lane & 31;          // 16B chunk within 512B plane row
    const uint4* Sv = (const uint4*)g_states;
    float acc0[8] = {0,0,0,0,0,0,0,0}, acc1[8] = {0,0,0,0,0,0,0,0}, acc2[8] = {0,0,0,0,0,0,0,0};
    int e0 = g_rowptr[node], deg = g_rowptr[node + 1] - e0;
    int m = deg + 1;
    int j = half;
    if (half == 0) {  // self term, then jump to virtual slot 2
        float di = g_dinv[node];
        float w0 = di * di;
        size_t base = (size_t)node * 96 + li;
        fma8(acc0, Sv[base], w0);
        fma8(acc1, Sv[base + 32], w0);
        fma8(acc2, Sv[base + 64], w0);
        j = 2;
    }
    #pragma unroll 2
    for (; j < m; j += 2) {
        int s = g_cidx[e0 + j - 1];
        float w = g_ewts[e0 + j - 1];
        size_t base = (size_t)s * 96 + li;
        uint4 v0 = Sv[base], v1 = Sv[base + 32], v2 = Sv[base + 64];
        fma8(acc0, v0, w); fma8(acc1, v1, w); fma8(acc2, v2, w);
    }
    // combine halves
    #pragma unroll
    for (int q = 0; q < 8; ++q) {
        acc0[q] += __shfl_xor(acc0[q], 32);
        acc1[q] += __shfl_xor(acc1[q], 32);
        acc2[q] += __shfl_xor(acc2[q], 32);
    }
    if (half == 0) {
        uint4* Av = (uint4*)g_agg3;
        size_t base = (size_t)node * 96 + li;
        uint4 o;
        unsigned* ou = (unsigned*)&o;
        #pragma unroll
        for (int q = 0; q < 4; ++q) ou[q] = (unsigned)f2h(acc0[q*2]) | ((unsigned)f2h(acc0[q*2+1]) << 16);
        Av[base] = o;
        #pragma unroll
        for (int q = 0; q < 4; ++q) ou[q] = (unsigned)f2h(acc1[q*2]) | ((unsigned)f2h(acc1[q*2+1]) << 16);
        Av[base + 32] = o;
        #pragma unroll
        for (int q = 0; q < 4; ++q) ou[q] = (unsigned)f2h(acc2[q*2]) | ((unsigned)f2h(acc2[q*2+1]) << 16);
        Av[base + 64] = o;
    }
}

// layer-0: x rows 128 f16 = 256 B = 16 lanes x uint4 -> 4 edges in flight.
// Writes g_agg3 compact [node][128].
__global__ __launch_bounds__(256) void agg128_k(int n) {
    int node = blockIdx.x * 4 + (threadIdx.x >> 6);
    if (node >= n) return;
    int lane = threadIdx.x & 63;
    int grp = lane >> 4;           // 4 edge slots
    int li  = lane & 15;
    const uint4* Xv = (const uint4*)g_xh;
    float acc[8] = {0,0,0,0,0,0,0,0};
    int e0 = g_rowptr[node], deg = g_rowptr[node + 1] - e0;
    int m = deg + 1;
    int j = grp;
    if (grp == 0) {
        float di = g_dinv[node];
        fma8(acc, Xv[(size_t)node * 16 + li], di * di);
        j = 4;
    }
    #pragma unroll 2
    for (; j < m; j += 4) {
        int s = g_cidx[e0 + j - 1];
        float w = g_ewts[e0 + j - 1];
        fma8(acc, Xv[(size_t)s * 16 + li], w);
    }
    #pragma unroll
    for (int q = 0; q < 8; ++q) {
        acc[q] += __shfl_xor(acc[q], 16);
        acc[q] += __shfl_xor(acc[q], 32);
    }
    if (grp == 0) {
        uint4 o; unsigned* ou = (unsigned*)&o;
        #pragma unroll
        for (int q = 0; q < 4; ++q) ou[q] = (unsigned)f2h(acc[q*2]) | ((unsigned)f2h(acc[q*2+1]) << 16);
        ((uint4*)g_agg3)[(size_t)node * 16 + li] = o;
    }
}

// ---------------- MFMA GEMM: props[r*768 + br*256 + c] = relu(A_row . Wt[c] + bias[c])
// A row addr = r*rowStride + br*brMul (layer0: rowStride=128, brMul=0).
template<int K>
__global__ __launch_bounds__(256) void gemm_mfma_k(int wsel, int rowStride, int brMul,
        const float* __restrict__ bias0, int n) {
    int br = blockIdx.y;
    const f16_t* A  = (const f16_t*)g_agg3 + (size_t)br * brMul;
    const f16_t* Wt = (wsel < 0) ? (const f16_t*)g_whin + (size_t)br * K * 256
                                 : (const f16_t*)g_whid + (size_t)(wsel + br) * K * 256;
    const float* bias = bias0 + (size_t)br * 256;
    u16* C = g_props + (size_t)br * 256;
    int t = threadIdx.x, l = t & 63, w = t >> 6;
    int row0 = blockIdx.x * 64;
    int c0 = w * 64;
    int mrow = l & 15;
    int kg = (l >> 4) * 8;
    f32x4 acc[4][4];
    #pragma unroll
    for (int rt = 0; rt < 4; ++rt)
        #pragma unroll
        for (int ct = 0; ct < 4; ++ct) acc[rt][ct] = (f32x4){0.f, 0.f, 0.f, 0.f};

    for (int k0 = 0; k0 < K; k0 += 32) {
        f16x8 af[4], bf[4];
        #pragma unroll
        for (int rt = 0; rt < 4; ++rt) {
            int r = row0 + rt * 16 + mrow;   // < NMAX always; stale rows masked at store
            af[rt] = *(const f16x8*)(A + (size_t)r * rowStride + k0 + kg);
        }
        #pragma unroll
        for (int ct = 0; ct < 4; ++ct) {
            int c = c0 + ct * 16 + mrow;
            bf[ct] = *(const f16x8*)(Wt + (size_t)c * K + k0 + kg);
        }
        #pragma unroll
        for (int rt = 0; rt < 4; ++rt)
            #pragma unroll
            for (int ct = 0; ct < 4; ++ct)
                acc[rt][ct] = __builtin_amdgcn_mfma_f32_16x16x32_f16(af[rt], bf[ct], acc[rt][ct], 0, 0, 0);
    }
    int rb = (l >> 4) * 4;
    #pragma unroll
    for (int ct = 0; ct < 4; ++ct) {
        int c = c0 + ct * 16 + mrow;
        float bv = bias[c];
        #pragma unroll
        for (int rt = 0; rt < 4; ++rt) {
            #pragma unroll
            for (int q = 0; q < 4; ++q) {
                int r = row0 + rt * 16 + rb + q;
                if (r < n) C[(size_t)r * 768 + c] = f2h(relu_f(acc[rt][ct][q] + bv));
            }
        }
    }
}

// ---------------- interleaved exact top-128 masks (u16 f16-bit search, 15 fixed iters) ----
template<int CNT>
__device__ __forceinline__ void topk_multi(const ushort4* hu, const float4* v, float4* out) {
    int lane = threadIdx.x & 63;
    unsigned lo[CNT], hi[CNT]; int cge[CNT];
    #pragma unroll
    for (int s = 0; s < CNT; ++s) { lo[s] = 0; hi[s] = 0x7BFF; cge[s] = 256; }
    for (int it = 0; it < 15; ++it) {
        #pragma unroll
        for (int s = 0; s < CNT; ++s) {
            unsigned mid = (lo[s] + hi[s] + 1) >> 1;
            int c = __popcll(__ballot(hu[s].x >= mid)) + __popcll(__ballot(hu[s].y >= mid))
                  + __popcll(__ballot(hu[s].z >= mid)) + __popcll(__ballot(hu[s].w >= mid));
            if (c >= 128) { lo[s] = mid; cge[s] = c; } else hi[s] = mid - 1;
        }
    }
    #pragma unroll
    for (int s = 0; s < CNT; ++s) {
        unsigned thr = lo[s];
        unsigned a0 = hu[s].x, a1 = hu[s].y, a2 = hu[s].z, a3 = hu[s].w;
        float4 r;
        if (cge[s] == 128) {   // wave-uniform branch
            r.x = (a0 >= thr) ? v[s].x : 0.f;
            r.y = (a1 >= thr) ? v[s].y : 0.f;
            r.z = (a2 >= thr) ? v[s].z : 0.f;
            r.w = (a3 >= thr) ? v[s].w : 0.f;
        } else {               // trim ties, keep lowest element indices
            ull b0 = __ballot(a0 == thr), b1 = __ballot(a1 == thr);
            ull b2 = __ballot(a2 == thr), b3 = __ballot(a3 == thr);
            int cgt = __popcll(__ballot(a0 > thr)) + __popcll(__ballot(a1 > thr))
                    + __popcll(__ballot(a2 > thr)) + __popcll(__ballot(a3 > thr));
            int need = 128 - cgt;
            ull below = (lane == 0) ? 0ull : (~0ull >> (64 - lane));
            int base = __popcll(b0 & below) + __popcll(b1 & below)
                     + __popcll(b2 & below) + __popcll(b3 & below);
            int o0 = (int)((b0 >> lane) & 1), o1 = (int)((b1 >> lane) & 1), o2 = (int)((b2 >> lane) & 1);
            int p0 = base, p1 = base + o0, p2 = p1 + o1, p3 = p2 + o2;
            r.x = (a0 > thr || (a0 == thr && p0 < need)) ? v[s].x : 0.f;
            r.y = (a1 > thr || (a1 == thr && p1 < need)) ? v[s].y : 0.f;
            r.z = (a2 > thr || (a2 == thr && p2 < need)) ? v[s].z : 0.f;
            r.w = (a3 > thr || (a3 == thr && p3 < need)) ? v[s].w : 0.f;
        }
        out[s] = r;
    }
}

__device__ __forceinline__ float4 dec4(ushort4 h) {
    float4 r; r.x = h2f(h.x); r.y = h2f(h.y); r.z = h2f(h.z); r.w = h2f(h.w);
    return r;
}
__device__ __forceinline__ void st4h(u16* p, size_t off, float4 v) {
    ushort4 o; o.x = f2h(v.x); o.y = f2h(v.y); o.z = f2h(v.z); o.w = f2h(v.w);
    ((ushort4*)p)[off] = o;
}

// layer 0: states <- relu(p_b + g*sum mask(p_b'))   [interleaved: node*192 + br*64 + lane]
__global__ __launch_bounds__(256) void fuse0_k(const float* __restrict__ gate_logit, int n) {
    int node = blockIdx.x * 4 + (threadIdx.x >> 6);
    if (node >= n) return;
    int lane = threadIdx.x & 63;
    size_t base4 = (size_t)node * 192 + lane;
    float g = 1.f / (1.f + expf(-gate_logit[0]));
    const ushort4* P = (const ushort4*)g_props;
    ushort4 hu[3]; float4 v[3], m[3];
    hu[0] = P[base4]; hu[1] = P[base4 + 64]; hu[2] = P[base4 + 128];
    v[0] = dec4(hu[0]); v[1] = dec4(hu[1]); v[2] = dec4(hu[2]);
    topk_multi<3>(hu, v, m);
    float4 o0, o1, o2;
    o0.x = relu_f(v[0].x + g * m[1].x); o0.y = relu_f(v[0].y + g * m[1].y);
    o0.z = relu_f(v[0].z + g * m[1].z); o0.w = relu_f(v[0].w + g * m[1].w);
    o1.x = relu_f(v[1].x + g * (m[0].x + m[2].x)); o1.y = relu_f(v[1].y + g * (m[0].y + m[2].y));
    o1.z = relu_f(v[1].z + g * (m[0].z + m[2].z)); o1.w = relu_f(v[1].w + g * (m[0].w + m[2].w));
    o2.x = relu_f(v[2].x + g * m[1].x); o2.y = relu_f(v[2].y + g * m[1].y);
    o2.z = relu_f(v[2].z + g * m[1].z); o2.w = relu_f(v[2].w + g * m[1].w);
    st4h(g_states, base4, o0); st4h(g_states, base4 + 64, o1); st4h(g_states, base4 + 128, o2);
}

// layers >=1: m[0..2]=mask(props), m[3..5]=mask(old states)
__global__ __launch_bounds__(256) void fuse_k(const float* __restrict__ gate_logit, int n) {
    int node = blockIdx.x * 4 + (threadIdx.x >> 6);
    if (node >= n) return;
    int lane = threadIdx.x & 63;
    size_t base4 = (size_t)node * 192 + lane;
    float g = 1.f / (1.f + expf(-gate_logit[0]));
    const ushort4* P = (const ushort4*)g_props;
    const ushort4* S = (const ushort4*)g_states;
    ushort4 hu[6]; float4 v[6], m[6];
    hu[0] = P[base4]; hu[1] = P[base4 + 64]; hu[2] = P[base4 + 128];
    hu[3] = S[base4]; hu[4] = S[base4 + 64]; hu[5] = S[base4 + 128];
    #pragma unroll
    for (int s = 0; s < 6; ++s) v[s] = dec4(hu[s]);
    topk_multi<6>(hu, v, m);
    float4 o0, o1, o2;
    o0.x = relu_f(v[0].x + g * (m[3].x + m[1].x + m[4].x));
    o0.y = relu_f(v[0].y + g * (m[3].y + m[1].y + m[4].y));
    o0.z = relu_f(v[0].z + g * (m[3].z + m[1].z + m[4].z));
    o0.w = relu_f(v[0].w + g * (m[3].w + m[1].w + m[4].w));
    o1.x = relu_f(v[1].x + g * (m[4].x + m[0].x + m[3].x + m[2].x + m[5].x));
    o1.y = relu_f(v[1].y + g * (m[4].y + m[0].y + m[3].y + m[2].y + m[5].y));
    o1.z = relu_f(v[1].z + g * (m[4].z + m[0].z + m[3].z + m[2].z + m[5].z));
    o1.w = relu_f(v[1].w + g * (m[4].w + m[0].w + m[3].w + m[2].w + m[5].w));
    o2.x = relu_f(v[2].x + g * (m[5].x + m[1].x + m[4].x));
    o2.y = relu_f(v[2].y + g * (m[5].y + m[1].y + m[4].y));
    o2.z = relu_f(v[2].z + g * (m[5].z + m[1].z + m[4].z));
    o2.w = relu_f(v[2].w + g * (m[5].w + m[1].w + m[4].w));
    st4h(g_states, base4, o0); st4h(g_states, base4 + 64, o1); st4h(g_states, base4 + 128, o2);
}

// ---------------- readout ----------------
__global__ void gbounds_k(const int* __restrict__ batch, int n) {
    int i = blockIdx.x * 256 + threadIdx.x;
    if (i >= n) return;
    int g = batch[i];
    atomicAdd(&g_gc[g], 1);
    if (i == 0 || batch[i - 1] != g) g_gs[g] = i;
}

__global__ __launch_bounds__(256) void greduce_k(float* __restrict__ outfin, int n) {
    int g = blockIdx.x, d = threadIdx.x;
    int st = g_gs[g], c = g_gc[g];
    float a = 0.f;
    for (int i = st; i < st + c; ++i) {
        size_t o = (size_t)i * 768 + d;
        a += h2f(g_states[o]) + h2f(g_states[o + 256]) + h2f(g_states[o + 512]);
    }
    float r = a / (3.0f * (float)(c > 0 ? c : 1));
    g_fin[g * 256 + d] = r;
    outfin[(size_t)g * 256 + d] = r;
}

__global__ void logits_k(const float* __restrict__ Wc, const float* __restrict__ bc,
                         float* __restrict__ out) {
    int idx = blockIdx.x * 256 + threadIdx.x;
    if (idx >= NGRAPH * NCLS) return;
    int g = idx / NCLS, c = idx % NCLS;
    float s = bc[c];
    for (int k = 0; k < 256; ++k) s += g_fin[g * 256 + k] * Wc[k * NCLS + c];
    out[idx] = s;
}

// ---------------- launch ----------------
extern "C" void kernel_launch(void* const* d_in, const int* in_sizes, int n_in,
                              void* d_out, int out_size, void* d_ws, size_t ws_size,
                              hipStream_t stream) {
    const float* x       = (const float*)d_in[0];
    const int*   eidx    = (const int*)d_in[1];
    const int*   batch   = (const int*)d_in[2];
    const float* Win     = (const float*)d_in[3];
    const float* b_in    = (const float*)d_in[4];
    const float* Whid    = (const float*)d_in[5];
    const float* bhid    = (const float*)d_in[6];
    const float* gate_l  = (const float*)d_in[7];
    const float* Wc      = (const float*)d_in[8];
    const float* bc      = (const float*)d_in[9];
    float* out = (float*)d_out;

    const int n = in_sizes[0] / INDIM;       // 50000
    const int E = in_sizes[1] / 2;           // 800000
    if (n > NMAX || E > EMAX) return;
    const int* erow = eidx;
    const int* ecol = eidx + E;

    float* outfin = out + NGRAPH * NCLS;

    const int TB = 256;
    dim3 b256(TB);
    int nblkN = (n + TB - 1) / TB;
    int eblk  = (E + TB - 1) / TB;
    int nblk4 = (n + 3) / 4;
    dim3 ggrid((n + 63) / 64, NB);

    // --- conversions + CSR build ---
    zero_cnt_k<<<nblkN, b256, 0, stream>>>(n);
    cvt_xh_k<<<(n * INDIM + TB - 1) / TB, b256, 0, stream>>>(x, n * INDIM);
    cvt_wt_k<<<(NB * INDIM * HIDDEN + TB - 1) / TB, b256, 0, stream>>>(Win, 0, INDIM, NB * INDIM * HIDDEN);
    cvt_wt_k<<<(9 * HIDDEN * HIDDEN + TB - 1) / TB, b256, 0, stream>>>(Whid, 1, HIDDEN, 9 * HIDDEN * HIDDEN);
    count_edges_k<<<eblk, b256, 0, stream>>>(ecol, E);
    dinv_k<<<nblkN, b256, 0, stream>>>(n);
    scan_k<<<1, 1024, 0, stream>>>(n);
    zero_cnt_k<<<nblkN, b256, 0, stream>>>(n);
    fill_csr_k<<<eblk, b256, 0, stream>>>(erow, ecol, E);

    // --- layer 0: agg(x) compact [n][128]; props = relu(agg @ Win_b + b_in_b) ---
    agg128_k<<<nblk4, b256, 0, stream>>>(n);
    gemm_mfma_k<INDIM><<<ggrid, b256, 0, stream>>>(-1, INDIM, 0, b_in, n);
    fuse0_k<<<nblk4, b256, 0, stream>>>(gate_l, n);

    // --- layers 1..3 (interleaved [node][br][256]) ---
    for (int l = 1; l < 4; ++l) {
        agg256x3_k<<<nblk4, b256, 0, stream>>>(n);
        gemm_mfma_k<HIDDEN><<<ggrid, b256, 0, stream>>>((l - 1) * NB, NB * HIDDEN, HIDDEN,
                bhid + (size_t)(l - 1) * NB * HIDDEN, n);
        fuse_k<<<nblk4, b256, 0, stream>>>(gate_l, n);
    }

    // --- readout ---
    zero_gk<<<1, 256, 0, stream>>>();
    gbounds_k<<<nblkN, b256, 0, stream>>>(batch, n);
    greduce_k<<<NGRAPH, b256, 0, stream>>>(outfin, n);
    logits_k<<<(NGRAPH * NCLS + TB - 1) / TB, b256, 0, stream>>>(Wc, bc, out);
}

// Round 12
// 1766.438 us; speedup vs baseline: 2.3233x; 1.0578x over previous
//
#include <hip/hip_runtime.h>
#include <hip/hip_fp16.h>

#define NB 3
#define HIDDEN 256
#define INDIM 128
#define NGRAPH 256
#define NCLS 10
#define NMAX 50048
#define EMAX 800000

typedef unsigned short u16;
typedef unsigned long long ull;
typedef _Float16 f16_t;
typedef f16_t f16x8 __attribute__((ext_vector_type(8)));
typedef float f32x4 __attribute__((ext_vector_type(4)));

// ---- static device scratch; intermediates stored f16, computed f32 ----
// Node-interleaved layout: [node][branch][256] (1536 B per node).
// Symbols referenced ONLY inside device code (host passing = r8 crash).
__device__ __align__(16) u16   g_states[(size_t)NMAX * NB * HIDDEN];
__device__ __align__(16) u16   g_props [(size_t)NMAX * NB * HIDDEN];
__device__ __align__(16) u16   g_agg3 [(size_t)NMAX * NB * HIDDEN];  // layer0: [node][128] compact
__device__ __align__(16) u16   g_xh    [(size_t)NMAX * INDIM];
__device__ __align__(16) u16   g_whin [(size_t)NB * INDIM * HIDDEN];  // Win^T f16 [b][col][k]
__device__ __align__(16) u16   g_whid [(size_t)9 * HIDDEN * HIDDEN];  // Whid^T f16 [(l-1)*3+b][col][k]
__device__ float g_fin   [NGRAPH * HIDDEN];
__device__ float g_dinv  [NMAX];
__device__ float g_ewts  [EMAX];
__device__ int   g_rowptr[NMAX + 1];
__device__ int   g_cidx  [EMAX];
__device__ int   g_cnt   [NMAX];
__device__ int   g_bsum  [64];
__device__ int   g_gs    [NGRAPH];
__device__ int   g_gc    [NGRAPH];

union HU { u16 u; __half h; };
__device__ __forceinline__ float h2f(u16 v) { HU x; x.u = v; return __half2float(x.h); }
__device__ __forceinline__ u16 f2h(float f) { HU x; x.h = __float2half_rn(f); return x.u; }
__device__ __forceinline__ float relu_f(float x) { return x > 0.f ? x : 0.f; }

// acc[0..7] += w * (8 f16 packed in uint4)
__device__ __forceinline__ void fma8(float* acc, uint4 v, float w) {
    unsigned uu[4] = {v.x, v.y, v.z, v.w};
    #pragma unroll
    for (int q = 0; q < 4; ++q) {
        HU lo, hi; lo.u = (u16)(uu[q] & 0xFFFFu); hi.u = (u16)(uu[q] >> 16);
        acc[q * 2 + 0] += w * __half2float(lo.h);
        acc[q * 2 + 1] += w * __half2float(hi.h);
    }
}

// ---------------- init / conversions ----------------
__global__ void zero_cnt_k(int n) {
    int i = blockIdx.x * 256 + threadIdx.x;
    if (i < n) g_cnt[i] = 0;
}
__global__ void zero_gk() {
    int i = threadIdx.x;
    g_gs[i] = 0; g_gc[i] = 0;
}
__global__ void cvt_xh_k(const float* __restrict__ x, int cnt4) {
    int i = blockIdx.x * 256 + threadIdx.x;
    if (i >= cnt4) return;
    float4 v = ((const float4*)x)[i];
    ushort4 o; o.x = f2h(v.x); o.y = f2h(v.y); o.z = f2h(v.z); o.w = f2h(v.w);
    ((ushort4*)g_xh)[i] = o;
}
// LDS-tiled transpose: src [B][K][256] f32 -> dst [B][256][K] f16.
// grid (K/32, 256/32, B), block 256.
__global__ void cvt_wt_k(const float* __restrict__ src, int which, int K) {
    __shared__ u16 tile[32][33];
    int k0 = blockIdx.x * 32, c0 = blockIdx.y * 32, b = blockIdx.z;
    int t = threadIdx.x;
    int tc = t & 31, tk = t >> 5;   // tk in 0..7
    const float* S = src + (size_t)b * K * 256;
    #pragma unroll
    for (int q = 0; q < 4; ++q) {
        int kk = tk * 4 + q;
        tile[kk][tc] = f2h(S[(size_t)(k0 + kk) * 256 + c0 + tc]);
    }
    __syncthreads();
    u16* D = (which ? g_whid : g_whin) + (size_t)b * K * 256;
    int kx = t & 31, cg = t >> 5;
    #pragma unroll
    for (int q = 0; q < 4; ++q) {
        int c = c0 + cg * 4 + q;
        D[(size_t)c * K + k0 + kx] = tile[kx][cg * 4 + q];
    }
}

// ---------------- CSR build ----------------
__global__ void count_edges_k(const int* __restrict__ col, int E) {
    int i = blockIdx.x * 256 + threadIdx.x;
    if (i < E) atomicAdd(&g_cnt[col[i]], 1);
}
__global__ void dinv_k(int n) {
    int i = blockIdx.x * 256 + threadIdx.x;
    if (i < n) g_dinv[i] = rsqrtf((float)(g_cnt[i] + 1));
}
// 3-phase multi-block exclusive scan of g_cnt into g_rowptr
__global__ __launch_bounds__(1024) void scan1_k(int n) {
    __shared__ int sm[1024];
    int blk = blockIdx.x, t = threadIdx.x;
    int i = blk * 1024 + t;
    int v = (i < n) ? g_cnt[i] : 0;
    sm[t] = v;
    __syncthreads();
    for (int off = 1; off < 1024; off <<= 1) {
        int u = (t >= off) ? sm[t - off] : 0;
        __syncthreads();
        sm[t] += u;
        __syncthreads();
    }
    if (i < n) g_rowptr[i + 1] = sm[t];
    if (t == 1023) g_bsum[blk] = sm[t];
    if (blk == 0 && t == 0) g_rowptr[0] = 0;
}
__global__ void scan2_k(int nblk) {   // 1 block, 64 threads (nblk <= 64)
    int t = threadIdx.x;
    int v = (t < nblk) ? g_bsum[t] : 0;
    #pragma unroll
    for (int off = 1; off < 64; off <<= 1) {
        int u = __shfl_up(v, off);
        if (t >= off) v += u;
    }
    if (t < nblk) g_bsum[t] = v;      // inclusive block sums
}
__global__ void scan3_k(int n) {
    int i = blockIdx.x * 256 + threadIdx.x;
    if (i >= n) return;
    int blk = i >> 10;
    if (blk > 0) g_rowptr[i + 1] += g_bsum[blk - 1];
}
__global__ void fill_csr_k(const int* __restrict__ row, const int* __restrict__ col, int E) {
    int i = blockIdx.x * 256 + threadIdx.x;
    if (i >= E) return;
    int r = row[i], c = col[i];
    int pos = g_rowptr[c] + atomicAdd(&g_cnt[c], 1);
    g_cidx[pos] = r;
    g_ewts[pos] = g_dinv[r] * g_dinv[c];
}

// ---------------- aggregation: interleaved layout, 2 edges in flight ----------------
// Node block = 96 uint4 (1536 B): plane p at +32*p. Virtual edge j=0 = self loop.
__global__ __launch_bounds__(256) void agg256x3_k(int n) {
    int node = blockIdx.x * 4 + (threadIdx.x >> 6);
    if (node >= n) return;
    int lane = threadIdx.x & 63;
    int half = lane >> 5;
    int li   = lane & 31;
    const uint4* Sv = (const uint4*)g_states;
    float acc0[8] = {0,0,0,0,0,0,0,0}, acc1[8] = {0,0,0,0,0,0,0,0}, acc2[8] = {0,0,0,0,0,0,0,0};
    int e0 = g_rowptr[node], deg = g_rowptr[node + 1] - e0;
    int m = deg + 1;
    int j = half;
    if (half == 0) {
        float di = g_dinv[node];
        float w0 = di * di;
        size_t base = (size_t)node * 96 + li;
        fma8(acc0, Sv[base], w0);
        fma8(acc1, Sv[base + 32], w0);
        fma8(acc2, Sv[base + 64], w0);
        j = 2;
    }
    #pragma unroll 2
    for (; j < m; j += 2) {
        int s = g_cidx[e0 + j - 1];
        float w = g_ewts[e0 + j - 1];
        size_t base = (size_t)s * 96 + li;
        uint4 v0 = Sv[base], v1 = Sv[base + 32], v2 = Sv[base + 64];
        fma8(acc0, v0, w); fma8(acc1, v1, w); fma8(acc2, v2, w);
    }
    #pragma unroll
    for (int q = 0; q < 8; ++q) {
        acc0[q] += __shfl_xor(acc0[q], 32);
        acc1[q] += __shfl_xor(acc1[q], 32);
        acc2[q] += __shfl_xor(acc2[q], 32);
    }
    if (half == 0) {
        uint4* Av = (uint4*)g_agg3;
        size_t base = (size_t)node * 96 + li;
        uint4 o;
        unsigned* ou = (unsigned*)&o;
        #pragma unroll
        for (int q = 0; q < 4; ++q) ou[q] = (unsigned)f2h(acc0[q*2]) | ((unsigned)f2h(acc0[q*2+1]) << 16);
        Av[base] = o;
        #pragma unroll
        for (int q = 0; q < 4; ++q) ou[q] = (unsigned)f2h(acc1[q*2]) | ((unsigned)f2h(acc1[q*2+1]) << 16);
        Av[base + 32] = o;
        #pragma unroll
        for (int q = 0; q < 4; ++q) ou[q] = (unsigned)f2h(acc2[q*2]) | ((unsigned)f2h(acc2[q*2+1]) << 16);
        Av[base + 64] = o;
    }
}

// layer-0: x rows 128 f16 = 256 B = 16 lanes x uint4 -> 4 edges in flight.
__global__ __launch_bounds__(256) void agg128_k(int n) {
    int node = blockIdx.x * 4 + (threadIdx.x >> 6);
    if (node >= n) return;
    int lane = threadIdx.x & 63;
    int grp = lane >> 4;
    int li  = lane & 15;
    const uint4* Xv = (const uint4*)g_xh;
    float acc[8] = {0,0,0,0,0,0,0,0};
    int e0 = g_rowptr[node], deg = g_rowptr[node + 1] - e0;
    int m = deg + 1;
    int j = grp;
    if (grp == 0) {
        float di = g_dinv[node];
        fma8(acc, Xv[(size_t)node * 16 + li], di * di);
        j = 4;
    }
    #pragma unroll 2
    for (; j < m; j += 4) {
        int s = g_cidx[e0 + j - 1];
        float w = g_ewts[e0 + j - 1];
        fma8(acc, Xv[(size_t)s * 16 + li], w);
    }
    #pragma unroll
    for (int q = 0; q < 8; ++q) {
        acc[q] += __shfl_xor(acc[q], 16);
        acc[q] += __shfl_xor(acc[q], 32);
    }
    if (grp == 0) {
        uint4 o; unsigned* ou = (unsigned*)&o;
        #pragma unroll
        for (int q = 0; q < 4; ++q) ou[q] = (unsigned)f2h(acc[q*2]) | ((unsigned)f2h(acc[q*2+1]) << 16);
        ((uint4*)g_agg3)[(size_t)node * 16 + li] = o;
    }
}

// ---------------- MFMA GEMM: props[r*768 + br*256 + c] = relu(A_row . Wt[c] + bias[c])
template<int K>
__global__ __launch_bounds__(256) void gemm_mfma_k(int wsel, int rowStride, int brMul,
        const float* __restrict__ bias0, int n) {
    int br = blockIdx.y;
    const f16_t* A  = (const f16_t*)g_agg3 + (size_t)br * brMul;
    const f16_t* Wt = (wsel < 0) ? (const f16_t*)g_whin + (size_t)br * K * 256
                                 : (const f16_t*)g_whid + (size_t)(wsel + br) * K * 256;
    const float* bias = bias0 + (size_t)br * 256;
    u16* C = g_props + (size_t)br * 256;
    int t = threadIdx.x, l = t & 63, w = t >> 6;
    int row0 = blockIdx.x * 64;
    int c0 = w * 64;
    int mrow = l & 15;
    int kg = (l >> 4) * 8;
    f32x4 acc[4][4];
    #pragma unroll
    for (int rt = 0; rt < 4; ++rt)
        #pragma unroll
        for (int ct = 0; ct < 4; ++ct) acc[rt][ct] = (f32x4){0.f, 0.f, 0.f, 0.f};

    for (int k0 = 0; k0 < K; k0 += 32) {
        f16x8 af[4], bf[4];
        #pragma unroll
        for (int rt = 0; rt < 4; ++rt) {
            int r = row0 + rt * 16 + mrow;
            af[rt] = *(const f16x8*)(A + (size_t)r * rowStride + k0 + kg);
        }
        #pragma unroll
        for (int ct = 0; ct < 4; ++ct) {
            int c = c0 + ct * 16 + mrow;
            bf[ct] = *(const f16x8*)(Wt + (size_t)c * K + k0 + kg);
        }
        #pragma unroll
        for (int rt = 0; rt < 4; ++rt)
            #pragma unroll
            for (int ct = 0; ct < 4; ++ct)
                acc[rt][ct] = __builtin_amdgcn_mfma_f32_16x16x32_f16(af[rt], bf[ct], acc[rt][ct], 0, 0, 0);
    }
    int rb = (l >> 4) * 4;
    #pragma unroll
    for (int ct = 0; ct < 4; ++ct) {
        int c = c0 + ct * 16 + mrow;
        float bv = bias[c];
        #pragma unroll
        for (int rt = 0; rt < 4; ++rt) {
            #pragma unroll
            for (int q = 0; q < 4; ++q) {
                int r = row0 + rt * 16 + rb + q;
                if (r < n) C[(size_t)r * 768 + c] = f2h(relu_f(acc[rt][ct][q] + bv));
            }
        }
    }
}

// ---------------- interleaved exact top-128 masks (u16 f16-bit search, 15 fixed iters) ----
template<int CNT>
__device__ __forceinline__ void topk_multi(const ushort4* hu, const float4* v, float4* out) {
    int lane = threadIdx.x & 63;
    unsigned lo[CNT], hi[CNT]; int cge[CNT];
    #pragma unroll
    for (int s = 0; s < CNT; ++s) { lo[s] = 0; hi[s] = 0x7BFF; cge[s] = 256; }
    for (int it = 0; it < 15; ++it) {
        #pragma unroll
        for (int s = 0; s < CNT; ++s) {
            unsigned mid = (lo[s] + hi[s] + 1) >> 1;
            int c = __popcll(__ballot(hu[s].x >= mid)) + __popcll(__ballot(hu[s].y >= mid))
                  + __popcll(__ballot(hu[s].z >= mid)) + __popcll(__ballot(hu[s].w >= mid));
            if (c >= 128) { lo[s] = mid; cge[s] = c; } else hi[s] = mid - 1;
        }
    }
    #pragma unroll
    for (int s = 0; s < CNT; ++s) {
        unsigned thr = lo[s];
        unsigned a0 = hu[s].x, a1 = hu[s].y, a2 = hu[s].z, a3 = hu[s].w;
        float4 r;
        if (cge[s] == 128) {
            r.x = (a0 >= thr) ? v[s].x : 0.f;
            r.y = (a1 >= thr) ? v[s].y : 0.f;
            r.z = (a2 >= thr) ? v[s].z : 0.f;
            r.w = (a3 >= thr) ? v[s].w : 0.f;
        } else {
            ull b0 = __ballot(a0 == thr), b1 = __ballot(a1 == thr);
            ull b2 = __ballot(a2 == thr), b3 = __ballot(a3 == thr);
            int cgt = __popcll(__ballot(a0 > thr)) + __popcll(__ballot(a1 > thr))
                    + __popcll(__ballot(a2 > thr)) + __popcll(__ballot(a3 > thr));
            int need = 128 - cgt;
            ull below = (lane == 0) ? 0ull : (~0ull >> (64 - lane));
            int base = __popcll(b0 & below) + __popcll(b1 & below)
                     + __popcll(b2 & below) + __popcll(b3 & below);
            int o0 = (int)((b0 >> lane) & 1), o1 = (int)((b1 >> lane) & 1), o2 = (int)((b2 >> lane) & 1);
            int p0 = base, p1 = base + o0, p2 = p1 + o1, p3 = p2 + o2;
            r.x = (a0 > thr || (a0 == thr && p0 < need)) ? v[s].x : 0.f;
            r.y = (a1 > thr || (a1 == thr && p1 < need)) ? v[s].y : 0.f;
            r.z = (a2 > thr || (a2 == thr && p2 < need)) ? v[s].z : 0.f;
            r.w = (a3 > thr || (a3 == thr && p3 < need)) ? v[s].w : 0.f;
        }
        out[s] = r;
    }
}

__device__ __forceinline__ float4 dec4(ushort4 h) {
    float4 r; r.x = h2f(h.x); r.y = h2f(h.y); r.z = h2f(h.z); r.w = h2f(h.w);
    return r;
}
__device__ __forceinline__ void st4h(u16* p, size_t off, float4 v) {
    ushort4 o; o.x = f2h(v.x); o.y = f2h(v.y); o.z = f2h(v.z); o.w = f2h(v.w);
    ((ushort4*)p)[off] = o;
}

// layer 0: states <- relu(p_b + g*sum mask(p_b'))   [interleaved: node*192 + br*64 + lane]
__global__ __launch_bounds__(256) void fuse0_k(const float* __restrict__ gate_logit, int n) {
    int node = blockIdx.x * 4 + (threadIdx.x >> 6);
    if (node >= n) return;
    int lane = threadIdx.x & 63;
    size_t base4 = (size_t)node * 192 + lane;
    float g = 1.f / (1.f + expf(-gate_logit[0]));
    const ushort4* P = (const ushort4*)g_props;
    ushort4 hu[3]; float4 v[3], m[3];
    hu[0] = P[base4]; hu[1] = P[base4 + 64]; hu[2] = P[base4 + 128];
    v[0] = dec4(hu[0]); v[1] = dec4(hu[1]); v[2] = dec4(hu[2]);
    topk_multi<3>(hu, v, m);
    float4 o0, o1, o2;
    o0.x = relu_f(v[0].x + g * m[1].x); o0.y = relu_f(v[0].y + g * m[1].y);
    o0.z = relu_f(v[0].z + g * m[1].z); o0.w = relu_f(v[0].w + g * m[1].w);
    o1.x = relu_f(v[1].x + g * (m[0].x + m[2].x)); o1.y = relu_f(v[1].y + g * (m[0].y + m[2].y));
    o1.z = relu_f(v[1].z + g * (m[0].z + m[2].z)); o1.w = relu_f(v[1].w + g * (m[0].w + m[2].w));
    o2.x = relu_f(v[2].x + g * m[1].x); o2.y = relu_f(v[2].y + g * m[1].y);
    o2.z = relu_f(v[2].z + g * m[1].z); o2.w = relu_f(v[2].w + g * m[1].w);
    st4h(g_states, base4, o0); st4h(g_states, base4 + 64, o1); st4h(g_states, base4 + 128, o2);
}

// layers >=1: m[0..2]=mask(props), m[3..5]=mask(old states)
__global__ __launch_bounds__(256) void fuse_k(const float* __restrict__ gate_logit, int n) {
    int node = blockIdx.x * 4 + (threadIdx.x >> 6);
    if (node >= n) return;
    int lane = threadIdx.x & 63;
    size_t base4 = (size_t)node * 192 + lane;
    float g = 1.f / (1.f + expf(-gate_logit[0]));
    const ushort4* P = (const ushort4*)g_props;
    const ushort4* S = (const ushort4*)g_states;
    ushort4 hu[6]; float4 v[6], m[6];
    hu[0] = P[base4]; hu[1] = P[base4 + 64]; hu[2] = P[base4 + 128];
    hu[3] = S[base4]; hu[4] = S[base4 + 64]; hu[5] = S[base4 + 128];
    #pragma unroll
    for (int s = 0; s < 6; ++s) v[s] = dec4(hu[s]);
    topk_multi<6>(hu, v, m);
    float4 o0, o1, o2;
    o0.x = relu_f(v[0].x + g * (m[3].x + m[1].x + m[4].x));
    o0.y = relu_f(v[0].y + g * (m[3].y + m[1].y + m[4].y));
    o0.z = relu_f(v[0].z + g * (m[3].z + m[1].z + m[4].z));
    o0.w = relu_f(v[0].w + g * (m[3].w + m[1].w + m[4].w));
    o1.x = relu_f(v[1].x + g * (m[4].x + m[0].x + m[3].x + m[2].x + m[5].x));
    o1.y = relu_f(v[1].y + g * (m[4].y + m[0].y + m[3].y + m[2].y + m[5].y));
    o1.z = relu_f(v[1].z + g * (m[4].z + m[0].z + m[3].z + m[2].z + m[5].z));
    o1.w = relu_f(v[1].w + g * (m[4].w + m[0].w + m[3].w + m[2].w + m[5].w));
    o2.x = relu_f(v[2].x + g * (m[5].x + m[1].x + m[4].x));
    o2.y = relu_f(v[2].y + g * (m[5].y + m[1].y + m[4].y));
    o2.z = relu_f(v[2].z + g * (m[5].z + m[1].z + m[4].z));
    o2.w = relu_f(v[2].w + g * (m[5].w + m[1].w + m[4].w));
    st4h(g_states, base4, o0); st4h(g_states, base4 + 64, o1); st4h(g_states, base4 + 128, o2);
}

// ---------------- readout ----------------
__global__ void gbounds_k(const int* __restrict__ batch, int n) {
    int i = blockIdx.x * 256 + threadIdx.x;
    if (i >= n) return;
    int g = batch[i];
    atomicAdd(&g_gc[g], 1);
    if (i == 0 || batch[i - 1] != g) g_gs[g] = i;
}

// vectorized: threads 0..191 own ushort4 slots of the 768-wide node row;
// LDS combines the 3 branch planes.
__global__ __launch_bounds__(256) void greduce_k(float* __restrict__ outfin, int n) {
    __shared__ float sums[768];
    int g = blockIdx.x, t = threadIdx.x;
    int st = g_gs[g], c = g_gc[g];
    if (t < 192) {
        const ushort4* S = (const ushort4*)g_states;
        float a0 = 0.f, a1 = 0.f, a2 = 0.f, a3 = 0.f;
        for (int i = st; i < st + c; ++i) {
            ushort4 v = S[(size_t)i * 192 + t];
            a0 += h2f(v.x); a1 += h2f(v.y); a2 += h2f(v.z); a3 += h2f(v.w);
        }
        sums[t * 4 + 0] = a0; sums[t * 4 + 1] = a1;
        sums[t * 4 + 2] = a2; sums[t * 4 + 3] = a3;
    }
    __syncthreads();
    float r = (sums[t] + sums[256 + t] + sums[512 + t]) / (3.0f * (float)(c > 0 ? c : 1));
    g_fin[g * 256 + t] = r;
    outfin[(size_t)g * 256 + t] = r;
}

__global__ void logits_k(const float* __restrict__ Wc, const float* __restrict__ bc,
                         float* __restrict__ out) {
    int idx = blockIdx.x * 256 + threadIdx.x;
    if (idx >= NGRAPH * NCLS) return;
    int g = idx / NCLS, c = idx % NCLS;
    float s = bc[c];
    for (int k = 0; k < 256; ++k) s += g_fin[g * 256 + k] * Wc[k * NCLS + c];
    out[idx] = s;
}

// ---------------- launch ----------------
extern "C" void kernel_launch(void* const* d_in, const int* in_sizes, int n_in,
                              void* d_out, int out_size, void* d_ws, size_t ws_size,
                              hipStream_t stream) {
    const float* x       = (const float*)d_in[0];
    const int*   eidx    = (const int*)d_in[1];
    const int*   batch   = (const int*)d_in[2];
    const float* Win     = (const float*)d_in[3];
    const float* b_in    = (const float*)d_in[4];
    const float* Whid    = (const float*)d_in[5];
    const float* bhid    = (const float*)d_in[6];
    const float* gate_l  = (const float*)d_in[7];
    const float* Wc      = (const float*)d_in[8];
    const float* bc      = (const float*)d_in[9];
    float* out = (float*)d_out;

    const int n = in_sizes[0] / INDIM;       // 50000
    const int E = in_sizes[1] / 2;           // 800000
    if (n > NMAX || E > EMAX) return;
    const int* erow = eidx;
    const int* ecol = eidx + E;

    float* outfin = out + NGRAPH * NCLS;

    const int TB = 256;
    dim3 b256(TB);
    int nblkN = (n + TB - 1) / TB;
    int eblk  = (E + TB - 1) / TB;
    int nblk4 = (n + 3) / 4;
    int sblk  = (n + 1023) / 1024;           // scan blocks (<= 49)
    dim3 ggrid((n + 63) / 64, NB);
    dim3 wgin(INDIM / 32, HIDDEN / 32, NB);
    dim3 wghid(HIDDEN / 32, HIDDEN / 32, 9);

    // --- conversions + CSR build ---
    zero_cnt_k<<<nblkN, b256, 0, stream>>>(n);
    cvt_xh_k<<<(n * INDIM / 4 + TB - 1) / TB, b256, 0, stream>>>(x, n * INDIM / 4);
    cvt_wt_k<<<wgin, b256, 0, stream>>>(Win, 0, INDIM);
    cvt_wt_k<<<wghid, b256, 0, stream>>>(Whid, 1, HIDDEN);
    count_edges_k<<<eblk, b256, 0, stream>>>(ecol, E);
    dinv_k<<<nblkN, b256, 0, stream>>>(n);
    scan1_k<<<sblk, 1024, 0, stream>>>(n);
    scan2_k<<<1, 64, 0, stream>>>(sblk);
    scan3_k<<<nblkN, b256, 0, stream>>>(n);
    zero_cnt_k<<<nblkN, b256, 0, stream>>>(n);
    fill_csr_k<<<eblk, b256, 0, stream>>>(erow, ecol, E);

    // --- layer 0: agg(x) compact [n][128]; props = relu(agg @ Win_b + b_in_b) ---
    agg128_k<<<nblk4, b256, 0, stream>>>(n);
    gemm_mfma_k<INDIM><<<ggrid, b256, 0, stream>>>(-1, INDIM, 0, b_in, n);
    fuse0_k<<<nblk4, b256, 0, stream>>>(gate_l, n);

    // --- layers 1..3 (interleaved [node][br][256]) ---
    for (int l = 1; l < 4; ++l) {
        agg256x3_k<<<nblk4, b256, 0, stream>>>(n);
        gemm_mfma_k<HIDDEN><<<ggrid, b256, 0, stream>>>((l - 1) * NB, NB * HIDDEN, HIDDEN,
                bhid + (size_t)(l - 1) * NB * HIDDEN, n);
        fuse_k<<<nblk4, b256, 0, stream>>>(gate_l, n);
    }

    // --- readout ---
    zero_gk<<<1, 256, 0, stream>>>();
    gbounds_k<<<nblkN, b256, 0, stream>>>(batch, n);
    greduce_k<<<NGRAPH, b256, 0, stream>>>(outfin, n);
    logits_k<<<(NGRAPH * NCLS + TB - 1) / TB, b256, 0, stream>>>(Wc, bc, out);
}

// Round 13
// 1694.734 us; speedup vs baseline: 2.4216x; 1.0423x over previous
//
#include <hip/hip_runtime.h>
#include <hip/hip_fp16.h>

#define NB 3
#define HIDDEN 256
#define INDIM 128
#define NGRAPH 256
#define NCLS 10
#define NMAX 50048
#define EMAX 800000

typedef unsigned short u16;
typedef unsigned long long ull;
typedef _Float16 f16_t;
typedef f16_t f16x8 __attribute__((ext_vector_type(8)));
typedef float f32x4 __attribute__((ext_vector_type(4)));

// ---- static device scratch; intermediates stored f16, computed f32 ----
// Node-interleaved layout: [node][branch][256] (1536 B per node).
// Symbols referenced ONLY inside device code (host passing = r8 crash).
__device__ __align__(16) u16   g_states[(size_t)NMAX * NB * HIDDEN];
__device__ __align__(16) u16   g_props [(size_t)NMAX * NB * HIDDEN];
__device__ __align__(16) u16   g_agg3 [(size_t)NMAX * NB * HIDDEN];  // layer0: [node][128] compact
__device__ __align__(16) u16   g_xh    [(size_t)NMAX * INDIM];
__device__ __align__(16) u16   g_whin [(size_t)NB * INDIM * HIDDEN];  // Win^T f16 [b][col][k]
__device__ __align__(16) u16   g_whid [(size_t)9 * HIDDEN * HIDDEN];  // Whid^T f16 [(l-1)*3+b][col][k]
__device__ float g_fin   [NGRAPH * HIDDEN];
__device__ float g_dinv  [NMAX];
__device__ float g_ewts  [EMAX];
__device__ int   g_rowptr[NMAX + 1];
__device__ int   g_cidx  [EMAX];
__device__ int   g_cnt   [NMAX];
__device__ int   g_bsum  [64];
__device__ int   g_gs    [NGRAPH];
__device__ int   g_gc    [NGRAPH];

union HU { u16 u; __half h; };
__device__ __forceinline__ float h2f(u16 v) { HU x; x.u = v; return __half2float(x.h); }
__device__ __forceinline__ u16 f2h(float f) { HU x; x.h = __float2half_rn(f); return x.u; }
__device__ __forceinline__ float relu_f(float x) { return x > 0.f ? x : 0.f; }

// acc[0..7] += w * (8 f16 packed in uint4)
__device__ __forceinline__ void fma8(float* acc, uint4 v, float w) {
    unsigned uu[4] = {v.x, v.y, v.z, v.w};
    #pragma unroll
    for (int q = 0; q < 4; ++q) {
        HU lo, hi; lo.u = (u16)(uu[q] & 0xFFFFu); hi.u = (u16)(uu[q] >> 16);
        acc[q * 2 + 0] += w * __half2float(lo.h);
        acc[q * 2 + 1] += w * __half2float(hi.h);
    }
}

// ---------------- init / conversions ----------------
__global__ void zero_cnt_k(int n) {
    int i = blockIdx.x * 256 + threadIdx.x;
    if (i < n) g_cnt[i] = 0;
}
__global__ void zero_gk() {
    int i = threadIdx.x;
    g_gs[i] = 0; g_gc[i] = 0;
}
__global__ void cvt_xh_k(const float* __restrict__ x, int cnt4) {
    int i = blockIdx.x * 256 + threadIdx.x;
    if (i >= cnt4) return;
    float4 v = ((const float4*)x)[i];
    ushort4 o; o.x = f2h(v.x); o.y = f2h(v.y); o.z = f2h(v.z); o.w = f2h(v.w);
    ((ushort4*)g_xh)[i] = o;
}
// LDS-tiled transpose: src [B][K][256] f32 -> dst [B][256][K] f16.
__global__ void cvt_wt_k(const float* __restrict__ src, int which, int K) {
    __shared__ u16 tile[32][33];
    int k0 = blockIdx.x * 32, c0 = blockIdx.y * 32, b = blockIdx.z;
    int t = threadIdx.x;
    int tc = t & 31, tk = t >> 5;
    const float* S = src + (size_t)b * K * 256;
    #pragma unroll
    for (int q = 0; q < 4; ++q) {
        int kk = tk * 4 + q;
        tile[kk][tc] = f2h(S[(size_t)(k0 + kk) * 256 + c0 + tc]);
    }
    __syncthreads();
    u16* D = (which ? g_whid : g_whin) + (size_t)b * K * 256;
    int kx = t & 31, cg = t >> 5;
    #pragma unroll
    for (int q = 0; q < 4; ++q) {
        int c = c0 + cg * 4 + q;
        D[(size_t)c * K + k0 + kx] = tile[kx][cg * 4 + q];
    }
}

// ---------------- CSR build ----------------
__global__ void count_edges_k(const int* __restrict__ col, int E) {
    int i = blockIdx.x * 256 + threadIdx.x;
    if (i < E) atomicAdd(&g_cnt[col[i]], 1);
}
__global__ void dinv_k(int n) {
    int i = blockIdx.x * 256 + threadIdx.x;
    if (i < n) g_dinv[i] = rsqrtf((float)(g_cnt[i] + 1));
}
__global__ __launch_bounds__(1024) void scan1_k(int n) {
    __shared__ int sm[1024];
    int blk = blockIdx.x, t = threadIdx.x;
    int i = blk * 1024 + t;
    int v = (i < n) ? g_cnt[i] : 0;
    sm[t] = v;
    __syncthreads();
    for (int off = 1; off < 1024; off <<= 1) {
        int u = (t >= off) ? sm[t - off] : 0;
        __syncthreads();
        sm[t] += u;
        __syncthreads();
    }
    if (i < n) g_rowptr[i + 1] = sm[t];
    if (t == 1023) g_bsum[blk] = sm[t];
    if (blk == 0 && t == 0) g_rowptr[0] = 0;
}
__global__ void scan2_k(int nblk) {
    int t = threadIdx.x;
    int v = (t < nblk) ? g_bsum[t] : 0;
    #pragma unroll
    for (int off = 1; off < 64; off <<= 1) {
        int u = __shfl_up(v, off);
        if (t >= off) v += u;
    }
    if (t < nblk) g_bsum[t] = v;
}
__global__ void scan3_k(int n) {
    int i = blockIdx.x * 256 + threadIdx.x;
    if (i >= n) return;
    int blk = i >> 10;
    if (blk > 0) g_rowptr[i + 1] += g_bsum[blk - 1];
}
__global__ void fill_csr_k(const int* __restrict__ row, const int* __restrict__ col, int E) {
    int i = blockIdx.x * 256 + threadIdx.x;
    if (i >= E) return;
    int r = row[i], c = col[i];
    int pos = g_rowptr[c] + atomicAdd(&g_cnt[c], 1);
    g_cidx[pos] = r;
    g_ewts[pos] = g_dinv[r] * g_dinv[c];
}

// ---------------- aggregation: interleaved layout, 2 edges in flight ----------------
__global__ __launch_bounds__(256) void agg256x3_k(int n) {
    int node = blockIdx.x * 4 + (threadIdx.x >> 6);
    if (node >= n) return;
    int lane = threadIdx.x & 63;
    int half = lane >> 5;
    int li   = lane & 31;
    const uint4* Sv = (const uint4*)g_states;
    float acc0[8] = {0,0,0,0,0,0,0,0}, acc1[8] = {0,0,0,0,0,0,0,0}, acc2[8] = {0,0,0,0,0,0,0,0};
    int e0 = g_rowptr[node], deg = g_rowptr[node + 1] - e0;
    int m = deg + 1;
    int j = half;
    if (half == 0) {
        float di = g_dinv[node];
        float w0 = di * di;
        size_t base = (size_t)node * 96 + li;
        fma8(acc0, Sv[base], w0);
        fma8(acc1, Sv[base + 32], w0);
        fma8(acc2, Sv[base + 64], w0);
        j = 2;
    }
    #pragma unroll 2
    for (; j < m; j += 2) {
        int s = g_cidx[e0 + j - 1];
        float w = g_ewts[e0 + j - 1];
        size_t base = (size_t)s * 96 + li;
        uint4 v0 = Sv[base], v1 = Sv[base + 32], v2 = Sv[base + 64];
        fma8(acc0, v0, w); fma8(acc1, v1, w); fma8(acc2, v2, w);
    }
    #pragma unroll
    for (int q = 0; q < 8; ++q) {
        acc0[q] += __shfl_xor(acc0[q], 32);
        acc1[q] += __shfl_xor(acc1[q], 32);
        acc2[q] += __shfl_xor(acc2[q], 32);
    }
    if (half == 0) {
        uint4* Av = (uint4*)g_agg3;
        size_t base = (size_t)node * 96 + li;
        uint4 o;
        unsigned* ou = (unsigned*)&o;
        #pragma unroll
        for (int q = 0; q < 4; ++q) ou[q] = (unsigned)f2h(acc0[q*2]) | ((unsigned)f2h(acc0[q*2+1]) << 16);
        Av[base] = o;
        #pragma unroll
        for (int q = 0; q < 4; ++q) ou[q] = (unsigned)f2h(acc1[q*2]) | ((unsigned)f2h(acc1[q*2+1]) << 16);
        Av[base + 32] = o;
        #pragma unroll
        for (int q = 0; q < 4; ++q) ou[q] = (unsigned)f2h(acc2[q*2]) | ((unsigned)f2h(acc2[q*2+1]) << 16);
        Av[base + 64] = o;
    }
}

__global__ __launch_bounds__(256) void agg128_k(int n) {
    int node = blockIdx.x * 4 + (threadIdx.x >> 6);
    if (node >= n) return;
    int lane = threadIdx.x & 63;
    int grp = lane >> 4;
    int li  = lane & 15;
    const uint4* Xv = (const uint4*)g_xh;
    float acc[8] = {0,0,0,0,0,0,0,0};
    int e0 = g_rowptr[node], deg = g_rowptr[node + 1] - e0;
    int m = deg + 1;
    int j = grp;
    if (grp == 0) {
        float di = g_dinv[node];
        fma8(acc, Xv[(size_t)node * 16 + li], di * di);
        j = 4;
    }
    #pragma unroll 2
    for (; j < m; j += 4) {
        int s = g_cidx[e0 + j - 1];
        float w = g_ewts[e0 + j - 1];
        fma8(acc, Xv[(size_t)s * 16 + li], w);
    }
    #pragma unroll
    for (int q = 0; q < 8; ++q) {
        acc[q] += __shfl_xor(acc[q], 16);
        acc[q] += __shfl_xor(acc[q], 32);
    }
    if (grp == 0) {
        uint4 o; unsigned* ou = (unsigned*)&o;
        #pragma unroll
        for (int q = 0; q < 4; ++q) ou[q] = (unsigned)f2h(acc[q*2]) | ((unsigned)f2h(acc[q*2+1]) << 16);
        ((uint4*)g_agg3)[(size_t)node * 16 + li] = o;
    }
}

// ---------------- MFMA GEMM ----------------
template<int K>
__global__ __launch_bounds__(256) void gemm_mfma_k(int wsel, int rowStride, int brMul,
        const float* __restrict__ bias0, int n) {
    int br = blockIdx.y;
    const f16_t* A  = (const f16_t*)g_agg3 + (size_t)br * brMul;
    const f16_t* Wt = (wsel < 0) ? (const f16_t*)g_whin + (size_t)br * K * 256
                                 : (const f16_t*)g_whid + (size_t)(wsel + br) * K * 256;
    const float* bias = bias0 + (size_t)br * 256;
    u16* C = g_props + (size_t)br * 256;
    int t = threadIdx.x, l = t & 63, w = t >> 6;
    int row0 = blockIdx.x * 64;
    int c0 = w * 64;
    int mrow = l & 15;
    int kg = (l >> 4) * 8;
    f32x4 acc[4][4];
    #pragma unroll
    for (int rt = 0; rt < 4; ++rt)
        #pragma unroll
        for (int ct = 0; ct < 4; ++ct) acc[rt][ct] = (f32x4){0.f, 0.f, 0.f, 0.f};

    for (int k0 = 0; k0 < K; k0 += 32) {
        f16x8 af[4], bf[4];
        #pragma unroll
        for (int rt = 0; rt < 4; ++rt) {
            int r = row0 + rt * 16 + mrow;
            af[rt] = *(const f16x8*)(A + (size_t)r * rowStride + k0 + kg);
        }
        #pragma unroll
        for (int ct = 0; ct < 4; ++ct) {
            int c = c0 + ct * 16 + mrow;
            bf[ct] = *(const f16x8*)(Wt + (size_t)c * K + k0 + kg);
        }
        #pragma unroll
        for (int rt = 0; rt < 4; ++rt)
            #pragma unroll
            for (int ct = 0; ct < 4; ++ct)
                acc[rt][ct] = __builtin_amdgcn_mfma_f32_16x16x32_f16(af[rt], bf[ct], acc[rt][ct], 0, 0, 0);
    }
    int rb = (l >> 4) * 4;
    #pragma unroll
    for (int ct = 0; ct < 4; ++ct) {
        int c = c0 + ct * 16 + mrow;
        float bv = bias[c];
        #pragma unroll
        for (int rt = 0; rt < 4; ++rt) {
            #pragma unroll
            for (int q = 0; q < 4; ++q) {
                int r = row0 + rt * 16 + rb + q;
                if (r < n) C[(size_t)r * 768 + c] = f2h(relu_f(acc[rt][ct][q] + bv));
            }
        }
    }
}

// ---------------- interleaved exact top-128 masks, early-exit search ----------------
// Identical results to the fixed-15-iteration version: once cge==128 (exact cut)
// or lo>=hi (converged to tie value), further iterations are no-ops and skipped.
template<int CNT>
__device__ __forceinline__ void topk_multi(const ushort4* hu, const float4* v, float4* out) {
    int lane = threadIdx.x & 63;
    unsigned lo[CNT], hi[CNT]; int cge[CNT];
    #pragma unroll
    for (int s = 0; s < CNT; ++s) {
        unsigned mx = max(max((unsigned)hu[s].x, (unsigned)hu[s].y),
                          max((unsigned)hu[s].z, (unsigned)hu[s].w));
        #pragma unroll
        for (int off = 32; off >= 1; off >>= 1)
            mx = max(mx, (unsigned)__shfl_xor((int)mx, off));
        lo[s] = 0; hi[s] = mx; cge[s] = 256;
    }
    for (int it = 0; it < 15; ++it) {
        #pragma unroll
        for (int s = 0; s < CNT; ++s) {
            if (cge[s] == 128 || lo[s] >= hi[s]) continue;   // wave-uniform skip
            unsigned mid = (lo[s] + hi[s] + 1) >> 1;
            int c = __popcll(__ballot(hu[s].x >= mid)) + __popcll(__ballot(hu[s].y >= mid))
                  + __popcll(__ballot(hu[s].z >= mid)) + __popcll(__ballot(hu[s].w >= mid));
            if (c >= 128) { lo[s] = mid; cge[s] = c; } else hi[s] = mid - 1;
        }
    }
    #pragma unroll
    for (int s = 0; s < CNT; ++s) {
        unsigned thr = lo[s];
        unsigned a0 = hu[s].x, a1 = hu[s].y, a2 = hu[s].z, a3 = hu[s].w;
        float4 r;
        if (cge[s] == 128) {
            r.x = (a0 >= thr) ? v[s].x : 0.f;
            r.y = (a1 >= thr) ? v[s].y : 0.f;
            r.z = (a2 >= thr) ? v[s].z : 0.f;
            r.w = (a3 >= thr) ? v[s].w : 0.f;
        } else {            // trim ties: keep lowest element indices among == thr
            ull b0 = __ballot(a0 == thr), b1 = __ballot(a1 == thr);
            ull b2 = __ballot(a2 == thr), b3 = __ballot(a3 == thr);
            int cgt = __popcll(__ballot(a0 > thr)) + __popcll(__ballot(a1 > thr))
                    + __popcll(__ballot(a2 > thr)) + __popcll(__ballot(a3 > thr));
            int need = 128 - cgt;
            ull below = (lane == 0) ? 0ull : (~0ull >> (64 - lane));
            int base = __popcll(b0 & below) + __popcll(b1 & below)
                     + __popcll(b2 & below) + __popcll(b3 & below);
            int o0 = (int)((b0 >> lane) & 1), o1 = (int)((b1 >> lane) & 1), o2 = (int)((b2 >> lane) & 1);
            int p0 = base, p1 = base + o0, p2 = p1 + o1, p3 = p2 + o2;
            r.x = (a0 > thr || (a0 == thr && p0 < need)) ? v[s].x : 0.f;
            r.y = (a1 > thr || (a1 == thr && p1 < need)) ? v[s].y : 0.f;
            r.z = (a2 > thr || (a2 == thr && p2 < need)) ? v[s].z : 0.f;
            r.w = (a3 > thr || (a3 == thr && p3 < need)) ? v[s].w : 0.f;
        }
        out[s] = r;
    }
}

__device__ __forceinline__ float4 dec4(ushort4 h) {
    float4 r; r.x = h2f(h.x); r.y = h2f(h.y); r.z = h2f(h.z); r.w = h2f(h.w);
    return r;
}
__device__ __forceinline__ void st4h(u16* p, size_t off, float4 v) {
    ushort4 o; o.x = f2h(v.x); o.y = f2h(v.y); o.z = f2h(v.z); o.w = f2h(v.w);
    ((ushort4*)p)[off] = o;
}

// layer 0: states <- relu(p_b + g*sum mask(p_b'))   [interleaved: node*192 + br*64 + lane]
__global__ __launch_bounds__(256) void fuse0_k(const float* __restrict__ gate_logit, int n) {
    int node = blockIdx.x * 4 + (threadIdx.x >> 6);
    if (node >= n) return;
    int lane = threadIdx.x & 63;
    size_t base4 = (size_t)node * 192 + lane;
    float g = 1.f / (1.f + expf(-gate_logit[0]));
    const ushort4* P = (const ushort4*)g_props;
    ushort4 hu[3]; float4 v[3], m[3];
    hu[0] = P[base4]; hu[1] = P[base4 + 64]; hu[2] = P[base4 + 128];
    v[0] = dec4(hu[0]); v[1] = dec4(hu[1]); v[2] = dec4(hu[2]);
    topk_multi<3>(hu, v, m);
    float4 o0, o1, o2;
    o0.x = relu_f(v[0].x + g * m[1].x); o0.y = relu_f(v[0].y + g * m[1].y);
    o0.z = relu_f(v[0].z + g * m[1].z); o0.w = relu_f(v[0].w + g * m[1].w);
    o1.x = relu_f(v[1].x + g * (m[0].x + m[2].x)); o1.y = relu_f(v[1].y + g * (m[0].y + m[2].y));
    o1.z = relu_f(v[1].z + g * (m[0].z + m[2].z)); o1.w = relu_f(v[1].w + g * (m[0].w + m[2].w));
    o2.x = relu_f(v[2].x + g * m[1].x); o2.y = relu_f(v[2].y + g * m[1].y);
    o2.z = relu_f(v[2].z + g * m[1].z); o2.w = relu_f(v[2].w + g * m[1].w);
    st4h(g_states, base4, o0); st4h(g_states, base4 + 64, o1); st4h(g_states, base4 + 128, o2);
}

// layers >=1: m[0..2]=mask(props), m[3..5]=mask(old states)
__global__ __launch_bounds__(256) void fuse_k(const float* __restrict__ gate_logit, int n) {
    int node = blockIdx.x * 4 + (threadIdx.x >> 6);
    if (node >= n) return;
    int lane = threadIdx.x & 63;
    size_t base4 = (size_t)node * 192 + lane;
    float g = 1.f / (1.f + expf(-gate_logit[0]));
    const ushort4* P = (const ushort4*)g_props;
    const ushort4* S = (const ushort4*)g_states;
    ushort4 hu[6]; float4 v[6], m[6];
    hu[0] = P[base4]; hu[1] = P[base4 + 64]; hu[2] = P[base4 + 128];
    hu[3] = S[base4]; hu[4] = S[base4 + 64]; hu[5] = S[base4 + 128];
    #pragma unroll
    for (int s = 0; s < 6; ++s) v[s] = dec4(hu[s]);
    topk_multi<6>(hu, v, m);
    float4 o0, o1, o2;
    o0.x = relu_f(v[0].x + g * (m[3].x + m[1].x + m[4].x));
    o0.y = relu_f(v[0].y + g * (m[3].y + m[1].y + m[4].y));
    o0.z = relu_f(v[0].z + g * (m[3].z + m[1].z + m[4].z));
    o0.w = relu_f(v[0].w + g * (m[3].w + m[1].w + m[4].w));
    o1.x = relu_f(v[1].x + g * (m[4].x + m[0].x + m[3].x + m[2].x + m[5].x));
    o1.y = relu_f(v[1].y + g * (m[4].y + m[0].y + m[3].y + m[2].y + m[5].y));
    o1.z = relu_f(v[1].z + g * (m[4].z + m[0].z + m[3].z + m[2].z + m[5].z));
    o1.w = relu_f(v[1].w + g * (m[4].w + m[0].w + m[3].w + m[2].w + m[5].w));
    o2.x = relu_f(v[2].x + g * (m[5].x + m[1].x + m[4].x));
    o2.y = relu_f(v[2].y + g * (m[5].y + m[1].y + m[4].y));
    o2.z = relu_f(v[2].z + g * (m[5].z + m[1].z + m[4].z));
    o2.w = relu_f(v[2].w + g * (m[5].w + m[1].w + m[4].w));
    st4h(g_states, base4, o0); st4h(g_states, base4 + 64, o1); st4h(g_states, base4 + 128, o2);
}

// ---------------- readout ----------------
__global__ void gbounds_k(const int* __restrict__ batch, int n) {
    int i = blockIdx.x * 256 + threadIdx.x;
    if (i >= n) return;
    int g = batch[i];
    atomicAdd(&g_gc[g], 1);
    if (i == 0 || batch[i - 1] != g) g_gs[g] = i;
}

__global__ __launch_bounds__(256) void greduce_k(float* __restrict__ outfin, int n) {
    __shared__ float sums[768];
    int g = blockIdx.x, t = threadIdx.x;
    int st = g_gs[g], c = g_gc[g];
    if (t < 192) {
        const ushort4* S = (const ushort4*)g_states;
        float a0 = 0.f, a1 = 0.f, a2 = 0.f, a3 = 0.f;
        for (int i = st; i < st + c; ++i) {
            ushort4 v = S[(size_t)i * 192 + t];
            a0 += h2f(v.x); a1 += h2f(v.y); a2 += h2f(v.z); a3 += h2f(v.w);
        }
        sums[t * 4 + 0] = a0; sums[t * 4 + 1] = a1;
        sums[t * 4 + 2] = a2; sums[t * 4 + 3] = a3;
    }
    __syncthreads();
    float r = (sums[t] + sums[256 + t] + sums[512 + t]) / (3.0f * (float)(c > 0 ? c : 1));
    g_fin[g * 256 + t] = r;
    outfin[(size_t)g * 256 + t] = r;
}

__global__ void logits_k(const float* __restrict__ Wc, const float* __restrict__ bc,
                         float* __restrict__ out) {
    int idx = blockIdx.x * 256 + threadIdx.x;
    if (idx >= NGRAPH * NCLS) return;
    int g = idx / NCLS, c = idx % NCLS;
    float s = bc[c];
    for (int k = 0; k < 256; ++k) s += g_fin[g * 256 + k] * Wc[k * NCLS + c];
    out[idx] = s;
}

// ---------------- launch ----------------
extern "C" void kernel_launch(void* const* d_in, const int* in_sizes, int n_in,
                              void* d_out, int out_size, void* d_ws, size_t ws_size,
                              hipStream_t stream) {
    const float* x       = (const float*)d_in[0];
    const int*   eidx    = (const int*)d_in[1];
    const int*   batch   = (const int*)d_in[2];
    const float* Win     = (const float*)d_in[3];
    const float* b_in    = (const float*)d_in[4];
    const float* Whid    = (const float*)d_in[5];
    const float* bhid    = (const float*)d_in[6];
    const float* gate_l  = (const float*)d_in[7];
    const float* Wc      = (const float*)d_in[8];
    const float* bc      = (const float*)d_in[9];
    float* out = (float*)d_out;

    const int n = in_sizes[0] / INDIM;       // 50000
    const int E = in_sizes[1] / 2;           // 800000
    if (n > NMAX || E > EMAX) return;
    const int* erow = eidx;
    const int* ecol = eidx + E;

    float* outfin = out + NGRAPH * NCLS;

    const int TB = 256;
    dim3 b256(TB);
    int nblkN = (n + TB - 1) / TB;
    int eblk  = (E + TB - 1) / TB;
    int nblk4 = (n + 3) / 4;
    int sblk  = (n + 1023) / 1024;
    dim3 ggrid((n + 63) / 64, NB);
    dim3 wgin(INDIM / 32, HIDDEN / 32, NB);
    dim3 wghid(HIDDEN / 32, HIDDEN / 32, 9);

    // --- conversions + CSR build ---
    zero_cnt_k<<<nblkN, b256, 0, stream>>>(n);
    cvt_xh_k<<<(n * INDIM / 4 + TB - 1) / TB, b256, 0, stream>>>(x, n * INDIM / 4);
    cvt_wt_k<<<wgin, b256, 0, stream>>>(Win, 0, INDIM);
    cvt_wt_k<<<wghid, b256, 0, stream>>>(Whid, 1, HIDDEN);
    count_edges_k<<<eblk, b256, 0, stream>>>(ecol, E);
    dinv_k<<<nblkN, b256, 0, stream>>>(n);
    scan1_k<<<sblk, 1024, 0, stream>>>(n);
    scan2_k<<<1, 64, 0, stream>>>(sblk);
    scan3_k<<<nblkN, b256, 0, stream>>>(n);
    zero_cnt_k<<<nblkN, b256, 0, stream>>>(n);
    fill_csr_k<<<eblk, b256, 0, stream>>>(erow, ecol, E);

    // --- layer 0 ---
    agg128_k<<<nblk4, b256, 0, stream>>>(n);
    gemm_mfma_k<INDIM><<<ggrid, b256, 0, stream>>>(-1, INDIM, 0, b_in, n);
    fuse0_k<<<nblk4, b256, 0, stream>>>(gate_l, n);

    // --- layers 1..3 ---
    for (int l = 1; l < 4; ++l) {
        agg256x3_k<<<nblk4, b256, 0, stream>>>(n);
        gemm_mfma_k<HIDDEN><<<ggrid, b256, 0, stream>>>((l - 1) * NB, NB * HIDDEN, HIDDEN,
                bhid + (size_t)(l - 1) * NB * HIDDEN, n);
        fuse_k<<<nblk4, b256, 0, stream>>>(gate_l, n);
    }

    // --- readout ---
    zero_gk<<<1, 256, 0, stream>>>();
    gbounds_k<<<nblkN, b256, 0, stream>>>(batch, n);
    greduce_k<<<NGRAPH, b256, 0, stream>>>(outfin, n);
    logits_k<<<(NGRAPH * NCLS + TB - 1) / TB, b256, 0, stream>>>(Wc, bc, out);
}